// Round 2
// baseline (913.994 us; speedup 1.0000x reference)
//
#include <hip/hip_runtime.h>
#include <hip/hip_bf16.h>
#include <stdint.h>

#define N_NODES 30000
#define N_PAD   30080   // 470 * 64
#define N_EDGES 100000
#define DIM     512
#define QKV_LD  1536    // packed [q | kA | vM] row stride
#define A_LDS_W 520     // 512 + 8 ushort pad -> 1040B row stride (bank stride 4)

typedef unsigned short ushort_t;
typedef __attribute__((ext_vector_type(8))) short short8;
typedef __attribute__((ext_vector_type(8))) unsigned short ushortx8;
typedef __attribute__((ext_vector_type(4))) float floatx4;

__device__ __forceinline__ float b2f(ushort_t b) { return __uint_as_float(((unsigned)b) << 16); }
__device__ __forceinline__ ushort_t f2b(float f) {
    unsigned u = __float_as_uint(f);
    u += 0x7FFFu + ((u >> 16) & 1u);   // round-nearest-even
    return (ushort_t)(u >> 16);
}

// ---------------- pad/convert h (f32) into padded bf16 buffers ----------------
__global__ __launch_bounds__(256) void pad_copy2(const float* __restrict__ h0,
                                                 const float* __restrict__ h1,
                                                 ushort_t* __restrict__ d0,
                                                 ushort_t* __restrict__ d1) {
    const int total = N_PAD * DIM / 4;
    const int valid = N_NODES * DIM / 4;
    int idx = blockIdx.x * 256 + threadIdx.x;
    if (idx >= total) return;
    const float* s = blockIdx.y ? h1 : h0;
    ushort_t* d = blockIdx.y ? d1 : d0;
    float4 v = make_float4(0.f, 0.f, 0.f, 0.f);
    if (idx < valid) v = ((const float4*)s)[idx];
    ushort_t o[4] = {f2b(v.x), f2b(v.y), f2b(v.z), f2b(v.w)};
    ((uint2*)d)[idx] = *(const uint2*)o;
}

// ---- fold per-head relation matrix into weight, write into concatenated B^T ----
__global__ __launch_bounds__(256) void fuse_weights4(const float* __restrict__ Wk0, const float* __restrict__ bk0,
                                                     const float* __restrict__ Wv0, const float* __restrict__ bv0,
                                                     const float* __restrict__ Wk1, const float* __restrict__ bk1,
                                                     const float* __restrict__ Wv1, const float* __restrict__ bv1,
                                                     const float* __restrict__ rel_att, const float* __restrict__ rel_msg,
                                                     ushort_t* __restrict__ cat_p, ushort_t* __restrict__ cat_a,
                                                     float* __restrict__ bias_p, float* __restrict__ bias_a) {
    const float *W, *bvec, *A;
    ushort_t* outw; float* outb;
    switch (blockIdx.y) {  // rel0 folds into author-side cat, rel1 into paper-side
        case 0: W = Wk1; bvec = bk1; A = rel_att;          outw = cat_a + 512 * DIM;  outb = bias_a + 512;  break;
        case 1: W = Wv1; bvec = bv1; A = rel_msg;          outw = cat_a + 1024 * DIM; outb = bias_a + 1024; break;
        case 2: W = Wk0; bvec = bk0; A = rel_att + 32768;  outw = cat_p + 512 * DIM;  outb = bias_p + 512;  break;
        default: W = Wv0; bvec = bv0; A = rel_msg + 32768; outw = cat_p + 1024 * DIM; outb = bias_p + 1024; break;
    }
    int idx = blockIdx.x * 256 + threadIdx.x;  // 512*512
    int n = idx & 511;
    int i = idx >> 9;
    int h = n >> 6, d = n & 63;
    const float* wrow = W + i * DIM + h * 64;
    const float* acol = A + h * 4096 + d;
    float s = 0.f;
#pragma unroll 8
    for (int c = 0; c < 64; ++c) s += wrow[c] * acol[c * 64];
    outw[n * DIM + i] = f2b(s);
    if (i == 0) {
        const float* bh = bvec + h * 64;
        float sb = 0.f;
        for (int c = 0; c < 64; ++c) sb += bh[c] * acol[c * 64];
        outb[n] = sb;
    }
}

// ---- 4x 512x512 transpose f32 -> bf16 ----
__global__ __launch_bounds__(256) void transpose4(const float* w0, const float* w1,
                                                  const float* w2, const float* w3,
                                                  ushort_t* o0, ushort_t* o1,
                                                  ushort_t* o2, ushort_t* o3) {
    const float* W; ushort_t* O;
    switch (blockIdx.y) {
        case 0: W = w0; O = o0; break;
        case 1: W = w1; O = o1; break;
        case 2: W = w2; O = o2; break;
        default: W = w3; O = o3; break;
    }
    __shared__ float tile[32][33];
    int bx = blockIdx.x & 15, by = blockIdx.x >> 4;
    int tx = threadIdx.x & 31, ty = threadIdx.x >> 5;  // 32x8
#pragma unroll
    for (int r = 0; r < 32; r += 8) tile[ty + r][tx] = W[(by * 32 + ty + r) * DIM + bx * 32 + tx];
    __syncthreads();
#pragma unroll
    for (int r = 0; r < 32; r += 8) O[(bx * 32 + ty + r) * DIM + by * 32 + tx] = f2b(tile[tx][ty + r]);
}

__global__ __launch_bounds__(256) void copy_biases(const float* bq0, const float* bq1,
                                                   float* bias_p, float* bias_a) {
    int i = blockIdx.x * 256 + threadIdx.x;  // 512
    bias_p[i] = bq0[i];
    bias_a[i] = bq1[i];
}

// ---------------- CSR build (both relations in one pass) ----------------
__global__ __launch_bounds__(256) void hist2(const int* __restrict__ dst0, const int* __restrict__ dst1,
                                             int* __restrict__ cnt) {
    int e = blockIdx.x * 256 + threadIdx.x;
    if (e >= 2 * N_EDGES) return;
    int rel = e >= N_EDGES;
    int d = (rel ? dst1 : dst0)[e - rel * N_EDGES];
    atomicAdd(&cnt[rel * N_NODES + d], 1);
}

__global__ __launch_bounds__(1024) void scan2(const int* __restrict__ cnt, int* __restrict__ row_ptr) {
    int rel = blockIdx.x;
    const int* c = cnt + rel * N_NODES;
    int* rp = row_ptr + rel * (N_NODES + 1);
    __shared__ int sums[1024];
    int tid = threadIdx.x;
    int base = tid * 32;
    int loc[32];
    int s = 0;
#pragma unroll
    for (int i = 0; i < 32; ++i) {
        int idx = base + i;
        int v = (idx < N_NODES) ? c[idx] : 0;
        s += v;
        loc[i] = s;
    }
    sums[tid] = s;
    __syncthreads();
    for (int off = 1; off < 1024; off <<= 1) {
        int add = (tid >= off) ? sums[tid - off] : 0;
        __syncthreads();
        sums[tid] += add;
        __syncthreads();
    }
    int pre = (tid > 0) ? sums[tid - 1] : 0;
    if (tid == 0) rp[0] = 0;
#pragma unroll
    for (int i = 0; i < 32; ++i) {
        int idx = base + i;
        if (idx < N_NODES) rp[idx + 1] = pre + loc[i];
    }
}

__global__ __launch_bounds__(256) void scatter2(const int* __restrict__ src0, const int* __restrict__ dst0,
                                                const int* __restrict__ src1, const int* __restrict__ dst1,
                                                const int* __restrict__ row_ptr,
                                                int* __restrict__ fill,
                                                int* __restrict__ colarr) {
    int e = blockIdx.x * 256 + threadIdx.x;
    if (e >= 2 * N_EDGES) return;
    int rel = e >= N_EDGES;
    int ei = e - rel * N_EDGES;
    int s = (rel ? src1 : src0)[ei];
    int d = (rel ? dst1 : dst0)[ei];
    int pos = atomicAdd(&fill[rel * N_NODES + d], 1);
    colarr[rel * N_EDGES + row_ptr[rel * (N_NODES + 1) + d] + pos] = s;
}

// ---------------- row-panel MFMA GEMM ----------------
// Block = 64 A-rows (full K=512 staged once in LDS, padded rows) x full N.
// B never touches LDS: per-lane 16B MFMA fragments straight from L2-resident weights.
// Zero barriers in the K-loop -> waves free-run, deep VMEM pipelining via TLP.
typedef const __attribute__((address_space(1))) unsigned int gu32;
typedef __attribute__((address_space(3))) unsigned int lu32;
__device__ __forceinline__ void gload_lds16(const void* g, void* l) {
    __builtin_amdgcn_global_load_lds((gu32*)g, (lu32*)l, 16, 0, 0);
}

// projection: C[M,1536] = A[M,512] @ BT[1536,512]^T + bias, bf16 out, ldc=1536
// 3 sequential 512-col chunks per block; A-LDS reused across chunks.
__global__ __launch_bounds__(256) void gemm_proj(const ushort_t* __restrict__ Ap, const ushort_t* __restrict__ Aa,
                                                 const ushort_t* __restrict__ Bp, const ushort_t* __restrict__ Ba,
                                                 const float* __restrict__ bias_p, const float* __restrict__ bias_a,
                                                 ushort_t* __restrict__ Cp, ushort_t* __restrict__ Ca) {
    int rel = blockIdx.y;
    const ushort_t* A = rel ? Aa : Ap;
    const ushort_t* BT = rel ? Ba : Bp;
    const float* bias = rel ? bias_a : bias_p;
    ushort_t* C = rel ? Ca : Cp;

    __shared__ alignas(16) ushort_t As[64 * A_LDS_W];
    int m0 = blockIdx.x * 64;
    int tid = threadIdx.x;
    int w = tid >> 6, l = tid & 63;
    // stage A: wave w stages rows [w*16, w*16+16), one fully-contiguous 1KB row per instr
#pragma unroll
    for (int t = 0; t < 16; ++t) {
        int r = w * 16 + t;
        gload_lds16(A + (size_t)(m0 + r) * DIM + l * 8, (char*)As + r * (A_LDS_W * 2));
    }
    int fr = l & 15, fq = l >> 4;
    const ushort_t* aF = As + fr * A_LDS_W + fq * 8;
    const ushort_t* Bw0 = BT + (size_t)(w * 128 + fr) * DIM + fq * 8;
    __syncthreads();   // only barrier in the kernel: A staged

#pragma unroll 1
    for (int c = 0; c < 3; ++c) {
        const ushort_t* Bw = Bw0 + (size_t)c * 512 * DIM;
        floatx4 acc[4][8] = {};
#pragma unroll 1
        for (int kt = 0; kt < 16; ++kt) {
            int k0 = kt * 32;
            short8 bf[8], af[4];
#pragma unroll
            for (int nj = 0; nj < 8; ++nj) bf[nj] = *(const short8*)(Bw + (size_t)nj * 16 * DIM + k0);
#pragma unroll
            for (int mi = 0; mi < 4; ++mi) af[mi] = *(const short8*)(aF + mi * 16 * A_LDS_W + k0);
#pragma unroll
            for (int mi = 0; mi < 4; ++mi)
#pragma unroll
                for (int nj = 0; nj < 8; ++nj)
                    acc[mi][nj] = __builtin_amdgcn_mfma_f32_16x16x32_bf16(af[mi], bf[nj], acc[mi][nj], 0, 0, 0);
        }
#pragma unroll
        for (int mi = 0; mi < 4; ++mi)
#pragma unroll
            for (int nj = 0; nj < 8; ++nj) {
                int col = c * 512 + w * 128 + nj * 16 + fr;
                float bc = bias[col];
#pragma unroll
                for (int r = 0; r < 4; ++r) {
                    int grow = m0 + mi * 16 + fq * 4 + r;
                    C[(size_t)grow * QKV_LD + col] = f2b(acc[mi][nj][r] + bc);
                }
            }
    }
}

// out: C[M,512] = T[M,512](lda=1536) @ WaT^T + ba, sigmoid-skip blend vs f32 residual
__global__ __launch_bounds__(256) void gemm_out(const ushort_t* __restrict__ Tp, const ushort_t* __restrict__ Ta,
                                                const ushort_t* __restrict__ Wp, const ushort_t* __restrict__ Wa,
                                                const float* __restrict__ ba0, const float* __restrict__ ba1,
                                                const float* __restrict__ hp, const float* __restrict__ ha,
                                                const float* __restrict__ skipv, float* __restrict__ out) {
    int rel = blockIdx.y;
    const ushort_t* A = rel ? Ta : Tp;
    const ushort_t* BT = rel ? Wa : Wp;
    const float* bias = rel ? ba1 : ba0;
    const float* Hres = rel ? ha : hp;
    float* C = out + (size_t)rel * N_NODES * DIM;

    __shared__ alignas(16) ushort_t As[64 * A_LDS_W];
    int m0 = blockIdx.x * 64;
    int tid = threadIdx.x;
    int w = tid >> 6, l = tid & 63;
#pragma unroll
    for (int t = 0; t < 16; ++t) {
        int r = w * 16 + t;
        gload_lds16(A + (size_t)(m0 + r) * QKV_LD + l * 8, (char*)As + r * (A_LDS_W * 2));
    }
    int fr = l & 15, fq = l >> 4;
    const ushort_t* aF = As + fr * A_LDS_W + fq * 8;
    const ushort_t* Bw = BT + (size_t)(w * 128 + fr) * DIM + fq * 8;
    __syncthreads();

    floatx4 acc[4][8] = {};
#pragma unroll 1
    for (int kt = 0; kt < 16; ++kt) {
        int k0 = kt * 32;
        short8 bf[8], af[4];
#pragma unroll
        for (int nj = 0; nj < 8; ++nj) bf[nj] = *(const short8*)(Bw + (size_t)nj * 16 * DIM + k0);
#pragma unroll
        for (int mi = 0; mi < 4; ++mi) af[mi] = *(const short8*)(aF + mi * 16 * A_LDS_W + k0);
#pragma unroll
        for (int mi = 0; mi < 4; ++mi)
#pragma unroll
            for (int nj = 0; nj < 8; ++nj)
                acc[mi][nj] = __builtin_amdgcn_mfma_f32_16x16x32_bf16(af[mi], bf[nj], acc[mi][nj], 0, 0, 0);
    }
    float sk = skipv[rel];
    float alpha = 1.f / (1.f + __expf(-sk));
    float onem = 1.f - alpha;
#pragma unroll
    for (int mi = 0; mi < 4; ++mi)
#pragma unroll
        for (int nj = 0; nj < 8; ++nj) {
            int col = w * 128 + nj * 16 + fr;
            float bc = bias[col];
#pragma unroll
            for (int r = 0; r < 4; ++r) {
                int grow = m0 + mi * 16 + fq * 4 + r;
                if (grow < N_NODES) {
                    float v = acc[mi][nj][r] + bc;
                    C[(size_t)grow * DIM + col] = v * alpha + Hres[(size_t)grow * DIM + col] * onem;
                }
            }
        }
}

// ------- per-node online-softmax aggregation: one wave = one node, all 8 heads -------
__global__ __launch_bounds__(256) void node_attn(const ushort_t* __restrict__ qkv_p,
                                                 ushort_t* __restrict__ qkv_p_mut,
                                                 const ushort_t* __restrict__ qkv_a,
                                                 ushort_t* __restrict__ qkv_a_mut,
                                                 const int* __restrict__ row_ptr,
                                                 const int* __restrict__ colarr,
                                                 const float* __restrict__ rel_pri) {
    int rel = blockIdx.y;
    const ushort_t* qkv_dst = rel ? qkv_a : qkv_p;
    ushort_t* t_out = rel ? qkv_a_mut : qkv_p_mut;
    const ushort_t* qkv_src = rel ? qkv_p : qkv_a;
    const int* rp = row_ptr + rel * (N_NODES + 1);
    const int* col = colarr + rel * N_EDGES;
    const float* pri = rel_pri + rel * 8;

    int w = threadIdx.x >> 6, l = threadIdx.x & 63;
    int n = blockIdx.x * 4 + w;  // < N_PAD
    float prih = pri[l >> 3] * 0.125f;  // pri[h] / sqrt(64)

    size_t qoff = (size_t)n * QKV_LD + l * 8;
    ushortx8 qr = *(const ushortx8*)(qkv_dst + qoff);
    float qd[8];
#pragma unroll
    for (int i = 0; i < 8; ++i) qd[i] = b2f(qr[i]);

    int lo = 0, hi = 0;
    if (n < N_NODES) { lo = rp[n]; hi = rp[n + 1]; }

    float m = -3.0e38f, s = 0.f;
    float acc[8] = {};
    int j = lo;
    ushortx8 kr, vr;
    if (j < hi) {
        int sn = col[j];
        const ushort_t* kb = qkv_src + (size_t)sn * QKV_LD + 512 + l * 8;
        kr = *(const ushortx8*)kb;
        vr = *(const ushortx8*)(kb + 512);
    }
    while (j < hi) {
        ushortx8 kc = kr, vc = vr;
        ++j;
        if (j < hi) {  // one-edge lookahead
            int sn = col[j];
            const ushort_t* kb = qkv_src + (size_t)sn * QKV_LD + 512 + l * 8;
            kr = *(const ushortx8*)kb;
            vr = *(const ushortx8*)(kb + 512);
        }
        float dot = 0.f;
#pragma unroll
        for (int i = 0; i < 8; ++i) dot += qd[i] * b2f(kc[i]);
        dot += __shfl_xor(dot, 1);
        dot += __shfl_xor(dot, 2);
        dot += __shfl_xor(dot, 4);   // full head-dot, replicated across 8-lane group
        float att = dot * prih;
        float mn = fmaxf(m, att);
        float e0 = __expf(m - mn);
        float e1 = __expf(att - mn);
        s = s * e0 + e1;
#pragma unroll
        for (int i = 0; i < 8; ++i) acc[i] = acc[i] * e0 + e1 * b2f(vc[i]);
        m = mn;
    }
    float inv = (hi > lo) ? 1.f / s : 0.f;
    ushortx8 o;
#pragma unroll
    for (int i = 0; i < 8; ++i) o[i] = f2b(acc[i] * inv);
    *(ushortx8*)(t_out + qoff) = o;  // overwrite q columns (disjoint from kA/vM reads)
}

// ---------------- host launch ----------------
extern "C" void kernel_launch(void* const* d_in, const int* in_sizes, int n_in,
                              void* d_out, int out_size, void* d_ws, size_t ws_size,
                              hipStream_t stream) {
    (void)in_sizes; (void)n_in; (void)out_size; (void)ws_size;
    const float* h_paper  = (const float*)d_in[0];
    const float* h_author = (const float*)d_in[1];
    const int* src0 = (const int*)d_in[2];
    const int* dst0 = (const int*)d_in[3];
    const int* src1 = (const int*)d_in[4];
    const int* dst1 = (const int*)d_in[5];
    const float* Wk0 = (const float*)d_in[6];  const float* bk0 = (const float*)d_in[7];
    const float* Wq0 = (const float*)d_in[8];  const float* bq0 = (const float*)d_in[9];
    const float* Wv0 = (const float*)d_in[10]; const float* bv0 = (const float*)d_in[11];
    const float* Wa0 = (const float*)d_in[12]; const float* ba0 = (const float*)d_in[13];
    const float* Wk1 = (const float*)d_in[14]; const float* bk1 = (const float*)d_in[15];
    const float* Wq1 = (const float*)d_in[16]; const float* bq1 = (const float*)d_in[17];
    const float* Wv1 = (const float*)d_in[18]; const float* bv1 = (const float*)d_in[19];
    const float* Wa1 = (const float*)d_in[20]; const float* ba1 = (const float*)d_in[21];
    const float* rel_att = (const float*)d_in[22];
    const float* rel_msg = (const float*)d_in[23];
    const float* rel_pri = (const float*)d_in[24];
    const float* skipv   = (const float*)d_in[25];
    float* out = (float*)d_out;

    char* p = (char*)d_ws;
    auto alloc = [&](size_t bytes) -> char* {
        char* r = p;
        p += (bytes + 255) & ~(size_t)255;
        return r;
    };
    ushort_t* hp_pad = (ushort_t*)alloc((size_t)N_PAD * DIM * 2);
    ushort_t* ha_pad = (ushort_t*)alloc((size_t)N_PAD * DIM * 2);
    ushort_t* qkv_p = (ushort_t*)alloc((size_t)N_PAD * QKV_LD * 2);
    ushort_t* qkv_a = (ushort_t*)alloc((size_t)N_PAD * QKV_LD * 2);
    ushort_t* cat_p = (ushort_t*)alloc((size_t)QKV_LD * DIM * 2);
    ushort_t* cat_a = (ushort_t*)alloc((size_t)QKV_LD * DIM * 2);
    ushort_t* WaT0 = (ushort_t*)alloc(DIM * DIM * 2);
    ushort_t* WaT1 = (ushort_t*)alloc(DIM * DIM * 2);
    float* bias_p = (float*)alloc(QKV_LD * 4);
    float* bias_a = (float*)alloc(QKV_LD * 4);
    int* cnt = (int*)alloc((size_t)4 * N_NODES * 4);  // cnt[2N] then fill[2N]
    int* fill = cnt + 2 * N_NODES;
    int* row_ptr = (int*)alloc((size_t)2 * (N_NODES + 1) * 4);
    int* colarr = (int*)alloc((size_t)2 * N_EDGES * 4);

    // prep
    pad_copy2<<<dim3((N_PAD * DIM / 4 + 255) / 256, 2), 256, 0, stream>>>(h_paper, h_author, hp_pad, ha_pad);
    fuse_weights4<<<dim3(1024, 4), 256, 0, stream>>>(Wk0, bk0, Wv0, bv0, Wk1, bk1, Wv1, bv1,
                                                     rel_att, rel_msg, cat_p, cat_a, bias_p, bias_a);
    transpose4<<<dim3(256, 4), 256, 0, stream>>>(Wq0, Wq1, Wa0, Wa1, cat_p, cat_a, WaT0, WaT1);
    copy_biases<<<2, 256, 0, stream>>>(bq0, bq1, bias_p, bias_a);

    // CSR (both relations)
    hipMemsetAsync(cnt, 0, (size_t)4 * N_NODES * 4, stream);
    hist2<<<(2 * N_EDGES + 255) / 256, 256, 0, stream>>>(dst0, dst1, cnt);
    scan2<<<2, 1024, 0, stream>>>(cnt, row_ptr);
    scatter2<<<(2 * N_EDGES + 255) / 256, 256, 0, stream>>>(src0, dst0, src1, dst1, row_ptr, fill, colarr);

    // projections: qkv_p = hp @ [Wq0 | Wk0*A1 | Wv0*M1], qkv_a = ha @ [Wq1 | Wk1*A0 | Wv1*M0]
    gemm_proj<<<dim3(N_PAD / 64, 2), 256, 0, stream>>>(hp_pad, ha_pad, cat_p, cat_a, bias_p, bias_a, qkv_p, qkv_a);

    // attention, both relations; t written into q columns of the dst-side qkv
    node_attn<<<dim3(N_PAD / 4, 2), 256, 0, stream>>>(qkv_p, qkv_p, qkv_a, qkv_a, row_ptr, colarr, rel_pri);

    // output GEMMs with sigmoid-skip blend
    gemm_out<<<dim3(N_PAD / 64, 2), 256, 0, stream>>>(qkv_p, qkv_a, WaT0, WaT1, ba0, ba1,
                                                      h_paper, h_author, skipv, out);
}

// Round 4
// 665.551 us; speedup vs baseline: 1.3733x; 1.3733x over previous
//
#include <hip/hip_runtime.h>
#include <hip/hip_bf16.h>
#include <stdint.h>

#define N_NODES 30000
#define N_PAD   30080   // 235 * 128
#define N_EDGES 100000
#define DIM     512
#define QKV_LD  1536    // packed [q | kA | vM] row stride

typedef unsigned short ushort_t;
typedef __attribute__((ext_vector_type(8))) short short8;
typedef __attribute__((ext_vector_type(8))) unsigned short ushortx8;
typedef __attribute__((ext_vector_type(4))) float floatx4;

__device__ __forceinline__ float b2f(ushort_t b) { return __uint_as_float(((unsigned)b) << 16); }
__device__ __forceinline__ ushort_t f2b(float f) {
    unsigned u = __float_as_uint(f);
    u += 0x7FFFu + ((u >> 16) & 1u);   // round-nearest-even
    return (ushort_t)(u >> 16);
}

// ---------------- pad/convert h (f32) into padded bf16 buffers ----------------
__global__ __launch_bounds__(256) void pad_copy2(const float* __restrict__ h0,
                                                 const float* __restrict__ h1,
                                                 ushort_t* __restrict__ d0,
                                                 ushort_t* __restrict__ d1) {
    const int total = N_PAD * DIM / 4;
    const int valid = N_NODES * DIM / 4;
    int idx = blockIdx.x * 256 + threadIdx.x;
    if (idx >= total) return;
    const float* s = blockIdx.y ? h1 : h0;
    ushort_t* d = blockIdx.y ? d1 : d0;
    float4 v = make_float4(0.f, 0.f, 0.f, 0.f);
    if (idx < valid) v = ((const float4*)s)[idx];
    ushort_t o[4] = {f2b(v.x), f2b(v.y), f2b(v.z), f2b(v.w)};
    ((uint2*)d)[idx] = *(const uint2*)o;
}

// ---- fold per-head relation matrix into weight, write into concatenated B^T ----
__global__ __launch_bounds__(256) void fuse_weights4(const float* __restrict__ Wk0, const float* __restrict__ bk0,
                                                     const float* __restrict__ Wv0, const float* __restrict__ bv0,
                                                     const float* __restrict__ Wk1, const float* __restrict__ bk1,
                                                     const float* __restrict__ Wv1, const float* __restrict__ bv1,
                                                     const float* __restrict__ rel_att, const float* __restrict__ rel_msg,
                                                     ushort_t* __restrict__ cat_p, ushort_t* __restrict__ cat_a,
                                                     float* __restrict__ bias_p, float* __restrict__ bias_a) {
    const float *W, *bvec, *A;
    ushort_t* outw; float* outb;
    switch (blockIdx.y) {  // rel0 folds into author-side cat, rel1 into paper-side
        case 0: W = Wk1; bvec = bk1; A = rel_att;          outw = cat_a + 512 * DIM;  outb = bias_a + 512;  break;
        case 1: W = Wv1; bvec = bv1; A = rel_msg;          outw = cat_a + 1024 * DIM; outb = bias_a + 1024; break;
        case 2: W = Wk0; bvec = bk0; A = rel_att + 32768;  outw = cat_p + 512 * DIM;  outb = bias_p + 512;  break;
        default: W = Wv0; bvec = bv0; A = rel_msg + 32768; outw = cat_p + 1024 * DIM; outb = bias_p + 1024; break;
    }
    int idx = blockIdx.x * 256 + threadIdx.x;  // 512*512
    int n = idx & 511;
    int i = idx >> 9;
    int h = n >> 6, d = n & 63;
    const float* wrow = W + i * DIM + h * 64;
    const float* acol = A + h * 4096 + d;
    float s = 0.f;
#pragma unroll 8
    for (int c = 0; c < 64; ++c) s += wrow[c] * acol[c * 64];
    outw[n * DIM + i] = f2b(s);
    if (i == 0) {
        const float* bh = bvec + h * 64;
        float sb = 0.f;
        for (int c = 0; c < 64; ++c) sb += bh[c] * acol[c * 64];
        outb[n] = sb;
    }
}

// ---- 4x 512x512 transpose f32 -> bf16 ----
__global__ __launch_bounds__(256) void transpose4(const float* w0, const float* w1,
                                                  const float* w2, const float* w3,
                                                  ushort_t* o0, ushort_t* o1,
                                                  ushort_t* o2, ushort_t* o3) {
    const float* W; ushort_t* O;
    switch (blockIdx.y) {
        case 0: W = w0; O = o0; break;
        case 1: W = w1; O = o1; break;
        case 2: W = w2; O = o2; break;
        default: W = w3; O = o3; break;
    }
    __shared__ float tile[32][33];
    int bx = blockIdx.x & 15, by = blockIdx.x >> 4;
    int tx = threadIdx.x & 31, ty = threadIdx.x >> 5;  // 32x8
#pragma unroll
    for (int r = 0; r < 32; r += 8) tile[ty + r][tx] = W[(by * 32 + ty + r) * DIM + bx * 32 + tx];
    __syncthreads();
#pragma unroll
    for (int r = 0; r < 32; r += 8) O[(bx * 32 + ty + r) * DIM + by * 32 + tx] = f2b(tile[tx][ty + r]);
}

__global__ __launch_bounds__(256) void copy_biases(const float* bq0, const float* bq1,
                                                   float* bias_p, float* bias_a) {
    int i = blockIdx.x * 256 + threadIdx.x;  // 512
    bias_p[i] = bq0[i];
    bias_a[i] = bq1[i];
}

// ---------------- CSR build (both relations in one pass) ----------------
__global__ __launch_bounds__(256) void hist2(const int* __restrict__ dst0, const int* __restrict__ dst1,
                                             int* __restrict__ cnt) {
    int e = blockIdx.x * 256 + threadIdx.x;
    if (e >= 2 * N_EDGES) return;
    int rel = e >= N_EDGES;
    int d = (rel ? dst1 : dst0)[e - rel * N_EDGES];
    atomicAdd(&cnt[rel * N_NODES + d], 1);
}

__global__ __launch_bounds__(1024) void scan2(const int* __restrict__ cnt, int* __restrict__ row_ptr) {
    int rel = blockIdx.x;
    const int* c = cnt + rel * N_NODES;
    int* rp = row_ptr + rel * (N_NODES + 1);
    __shared__ int sums[1024];
    int tid = threadIdx.x;
    int base = tid * 32;
    int loc[32];
    int s = 0;
#pragma unroll
    for (int i = 0; i < 32; ++i) {
        int idx = base + i;
        int v = (idx < N_NODES) ? c[idx] : 0;
        s += v;
        loc[i] = s;
    }
    sums[tid] = s;
    __syncthreads();
    for (int off = 1; off < 1024; off <<= 1) {
        int add = (tid >= off) ? sums[tid - off] : 0;
        __syncthreads();
        sums[tid] += add;
        __syncthreads();
    }
    int pre = (tid > 0) ? sums[tid - 1] : 0;
    if (tid == 0) rp[0] = 0;
#pragma unroll
    for (int i = 0; i < 32; ++i) {
        int idx = base + i;
        if (idx < N_NODES) rp[idx + 1] = pre + loc[i];
    }
}

__global__ __launch_bounds__(256) void scatter2(const int* __restrict__ src0, const int* __restrict__ dst0,
                                                const int* __restrict__ src1, const int* __restrict__ dst1,
                                                const int* __restrict__ row_ptr,
                                                int* __restrict__ fill,
                                                int* __restrict__ colarr) {
    int e = blockIdx.x * 256 + threadIdx.x;
    if (e >= 2 * N_EDGES) return;
    int rel = e >= N_EDGES;
    int ei = e - rel * N_EDGES;
    int s = (rel ? src1 : src0)[ei];
    int d = (rel ? dst1 : dst0)[ei];
    int pos = atomicAdd(&fill[rel * N_NODES + d], 1);
    colarr[rel * N_EDGES + row_ptr[rel * (N_NODES + 1) + d] + pos] = s;
}

// ---------------- MFMA GEMM core (128x128 tile, BK=32, 8 waves of 32x64) ----------------
// 512 threads / 8 thin waves per block -> acc halves to 32 regs/thread vs R0's 64,
// raising the resource-limited resident-wave count.
// Staging: thread t handles matrix (t<256 ? A : B), granule g=t&255 covers
// rows srow=g>>2 AND srow+64 (2 gloads/thread/K-step; full 8KB tile coverage).
typedef const __attribute__((address_space(1))) unsigned int gu32;
typedef __attribute__((address_space(3))) unsigned int lu32;
__device__ __forceinline__ void gload_lds16(const void* g, void* l) {
    __builtin_amdgcn_global_load_lds((gu32*)g, (lu32*)l, 16, 0, 0);
}

// projection: C[M,1536] = A[M,512] @ BT[1536,512]^T + bias, bf16 out, ldc=1536
// grid: 1D 5640 = 8 XCD chunks of 705; decode rel / m-blk / n-blk inside.
__global__ __launch_bounds__(512) void gemm_proj(const ushort_t* __restrict__ Ap, const ushort_t* __restrict__ Aa,
                                                 const ushort_t* __restrict__ Bp, const ushort_t* __restrict__ Ba,
                                                 const float* __restrict__ bias_p, const float* __restrict__ bias_a,
                                                 ushort_t* __restrict__ Cp, ushort_t* __restrict__ Ca) {
    int bid = blockIdx.x;
    int lin = (bid & 7) * 705 + (bid >> 3);   // XCD-chunked bijection (5640 = 8*705)
    int rel = lin >= 2820;
    int r = lin - rel * 2820;
    int my = r / 12, nx = r - my * 12;
    const ushort_t* A = rel ? Aa : Ap;
    const ushort_t* BT = rel ? Ba : Bp;
    const float* bias = rel ? bias_a : bias_p;
    ushort_t* C = rel ? Ca : Cp;

    __shared__ alignas(16) ushort_t As[128 * 32];
    __shared__ alignas(16) ushort_t Bs[128 * 32];
    int n0 = nx * 128, m0 = my * 128;
    int tid = threadIdx.x;
    int w = tid >> 6, l = tid & 63;
    int wr = w >> 1, wc = w & 1;          // wave covers rows [wr*32,+32), cols [wc*64,+64)
    int fr = l & 15, fq = l >> 4;
    floatx4 acc[2][4] = {};
    const ushort_t* aF = &As[(wr * 32 + fr) * 32 + fq * 8];
    const ushort_t* bF = &Bs[(wc * 64 + fr) * 32 + fq * 8];
    // staging map: thread t stages granules g and g+256 (rows srow, srow+64)
    int g = tid & 255;
    int srow = g >> 2, sc0 = (g & 3) * 8;
    const ushort_t* gsrc0 = (tid < 256) ? (A + (size_t)(m0 + srow) * DIM + sc0)
                                        : (BT + (size_t)(n0 + srow) * DIM + sc0);
    const ushort_t* gsrc1 = gsrc0 + (size_t)64 * DIM;
    char* ldst = (tid < 256) ? ((char*)As + g * 16) : ((char*)Bs + g * 16);

#pragma unroll 1
    for (int kt = 0; kt < 16; ++kt) {
        int k0 = kt * 32;
        if (kt) __syncthreads();
        gload_lds16(gsrc0 + k0, ldst);
        gload_lds16(gsrc1 + k0, ldst + 4096);
        __syncthreads();
        short8 af[2], bf[4];
#pragma unroll
        for (int i = 0; i < 2; ++i) af[i] = *(const short8*)(aF + i * 16 * 32);
#pragma unroll
        for (int j = 0; j < 4; ++j) bf[j] = *(const short8*)(bF + j * 16 * 32);
#pragma unroll
        for (int i = 0; i < 2; ++i)
#pragma unroll
            for (int j = 0; j < 4; ++j)
                acc[i][j] = __builtin_amdgcn_mfma_f32_16x16x32_bf16(af[i], bf[j], acc[i][j], 0, 0, 0);
    }
#pragma unroll
    for (int i = 0; i < 2; ++i)
#pragma unroll
        for (int j = 0; j < 4; ++j) {
            int col = n0 + wc * 64 + j * 16 + fr;
            float bc = bias[col];
#pragma unroll
            for (int rr = 0; rr < 4; ++rr) {
                int grow = m0 + wr * 32 + i * 16 + fq * 4 + rr;
                C[(size_t)grow * QKV_LD + col] = f2b(acc[i][j][rr] + bc);
            }
        }
}

// out: C[M,512] = T[M,512](lda=1536) @ WaT^T + ba, sigmoid-skip blend vs f32 residual
// grid: 1D 1880 = 8 XCD chunks of 235.
__global__ __launch_bounds__(512) void gemm_out(const ushort_t* __restrict__ Tp, const ushort_t* __restrict__ Ta,
                                                const ushort_t* __restrict__ Wp, const ushort_t* __restrict__ Wa,
                                                const float* __restrict__ ba0, const float* __restrict__ ba1,
                                                const float* __restrict__ hp, const float* __restrict__ ha,
                                                const float* __restrict__ skipv, float* __restrict__ out) {
    int bid = blockIdx.x;
    int lin = (bid & 7) * 235 + (bid >> 3);   // XCD-chunked bijection (1880 = 8*235)
    int rel = lin >= 940;
    int r = lin - rel * 940;
    int my = r >> 2, nx = r & 3;
    const ushort_t* A = rel ? Ta : Tp;
    const ushort_t* BT = rel ? Wa : Wp;
    const float* bias = rel ? ba1 : ba0;
    const float* Hres = rel ? ha : hp;
    float* C = out + (size_t)rel * N_NODES * DIM;

    __shared__ alignas(16) ushort_t As[128 * 32];
    __shared__ alignas(16) ushort_t Bs[128 * 32];
    int n0 = nx * 128, m0 = my * 128;
    int tid = threadIdx.x;
    int w = tid >> 6, l = tid & 63;
    int wr = w >> 1, wc = w & 1;
    int fr = l & 15, fq = l >> 4;
    floatx4 acc[2][4] = {};
    const ushort_t* aF = &As[(wr * 32 + fr) * 32 + fq * 8];
    const ushort_t* bF = &Bs[(wc * 64 + fr) * 32 + fq * 8];
    int g = tid & 255;
    int srow = g >> 2, sc0 = (g & 3) * 8;
    const ushort_t* gsrc0 = (tid < 256) ? (A + (size_t)(m0 + srow) * QKV_LD + sc0)
                                        : (BT + (size_t)(n0 + srow) * DIM + sc0);
    const ushort_t* gsrc1 = gsrc0 + (size_t)64 * ((tid < 256) ? QKV_LD : DIM);
    char* ldst = (tid < 256) ? ((char*)As + g * 16) : ((char*)Bs + g * 16);

#pragma unroll 1
    for (int kt = 0; kt < 16; ++kt) {
        int k0 = kt * 32;
        if (kt) __syncthreads();
        gload_lds16(gsrc0 + k0, ldst);
        gload_lds16(gsrc1 + k0, ldst + 4096);
        __syncthreads();
        short8 af[2], bf[4];
#pragma unroll
        for (int i = 0; i < 2; ++i) af[i] = *(const short8*)(aF + i * 16 * 32);
#pragma unroll
        for (int j = 0; j < 4; ++j) bf[j] = *(const short8*)(bF + j * 16 * 32);
#pragma unroll
        for (int i = 0; i < 2; ++i)
#pragma unroll
            for (int j = 0; j < 4; ++j)
                acc[i][j] = __builtin_amdgcn_mfma_f32_16x16x32_bf16(af[i], bf[j], acc[i][j], 0, 0, 0);
    }
    float sk = skipv[rel];
    float alpha = 1.f / (1.f + __expf(-sk));
    float onem = 1.f - alpha;
#pragma unroll
    for (int i = 0; i < 2; ++i)
#pragma unroll
        for (int j = 0; j < 4; ++j) {
            int col = n0 + wc * 64 + j * 16 + fr;
            float bc = bias[col];
#pragma unroll
            for (int rr = 0; rr < 4; ++rr) {
                int grow = m0 + wr * 32 + i * 16 + fq * 4 + rr;
                if (grow < N_NODES) {
                    float v = acc[i][j][rr] + bc;
                    C[(size_t)grow * DIM + col] = v * alpha + Hres[(size_t)grow * DIM + col] * onem;
                }
            }
        }
}

// ------- per-node online-softmax aggregation: one wave = one node, all 8 heads -------
__global__ __launch_bounds__(256) void node_attn(const ushort_t* __restrict__ qkv_p,
                                                 ushort_t* __restrict__ qkv_p_mut,
                                                 const ushort_t* __restrict__ qkv_a,
                                                 ushort_t* __restrict__ qkv_a_mut,
                                                 const int* __restrict__ row_ptr,
                                                 const int* __restrict__ colarr,
                                                 const float* __restrict__ rel_pri) {
    int rel = blockIdx.y;
    const ushort_t* qkv_dst = rel ? qkv_a : qkv_p;
    ushort_t* t_out = rel ? qkv_a_mut : qkv_p_mut;
    const ushort_t* qkv_src = rel ? qkv_p : qkv_a;
    const int* rp = row_ptr + rel * (N_NODES + 1);
    const int* col = colarr + rel * N_EDGES;
    const float* pri = rel_pri + rel * 8;

    int w = threadIdx.x >> 6, l = threadIdx.x & 63;
    int n = blockIdx.x * 4 + w;  // < N_PAD
    float prih = pri[l >> 3] * 0.125f;  // pri[h] / sqrt(64)

    size_t qoff = (size_t)n * QKV_LD + l * 8;
    ushortx8 qr = *(const ushortx8*)(qkv_dst + qoff);
    float qd[8];
#pragma unroll
    for (int i = 0; i < 8; ++i) qd[i] = b2f(qr[i]);

    int lo = 0, hi = 0;
    if (n < N_NODES) { lo = rp[n]; hi = rp[n + 1]; }

    float m = -3.0e38f, s = 0.f;
    float acc[8] = {};
    int j = lo;
    ushortx8 kr, vr;
    if (j < hi) {
        int sn = col[j];
        const ushort_t* kb = qkv_src + (size_t)sn * QKV_LD + 512 + l * 8;
        kr = *(const ushortx8*)kb;
        vr = *(const ushortx8*)(kb + 512);
    }
    while (j < hi) {
        ushortx8 kc = kr, vc = vr;
        ++j;
        if (j < hi) {  // one-edge lookahead
            int sn = col[j];
            const ushort_t* kb = qkv_src + (size_t)sn * QKV_LD + 512 + l * 8;
            kr = *(const ushortx8*)kb;
            vr = *(const ushortx8*)(kb + 512);
        }
        float dot = 0.f;
#pragma unroll
        for (int i = 0; i < 8; ++i) dot += qd[i] * b2f(kc[i]);
        dot += __shfl_xor(dot, 1);
        dot += __shfl_xor(dot, 2);
        dot += __shfl_xor(dot, 4);   // full head-dot, replicated across 8-lane group
        float att = dot * prih;
        float mn = fmaxf(m, att);
        float e0 = __expf(m - mn);
        float e1 = __expf(att - mn);
        s = s * e0 + e1;
#pragma unroll
        for (int i = 0; i < 8; ++i) acc[i] = acc[i] * e0 + e1 * b2f(vc[i]);
        m = mn;
    }
    float inv = (hi > lo) ? 1.f / s : 0.f;
    ushortx8 o;
#pragma unroll
    for (int i = 0; i < 8; ++i) o[i] = f2b(acc[i] * inv);
    *(ushortx8*)(t_out + qoff) = o;  // overwrite q columns (disjoint from kA/vM reads)
}

// ---------------- host launch ----------------
extern "C" void kernel_launch(void* const* d_in, const int* in_sizes, int n_in,
                              void* d_out, int out_size, void* d_ws, size_t ws_size,
                              hipStream_t stream) {
    (void)in_sizes; (void)n_in; (void)out_size; (void)ws_size;
    const float* h_paper  = (const float*)d_in[0];
    const float* h_author = (const float*)d_in[1];
    const int* src0 = (const int*)d_in[2];
    const int* dst0 = (const int*)d_in[3];
    const int* src1 = (const int*)d_in[4];
    const int* dst1 = (const int*)d_in[5];
    const float* Wk0 = (const float*)d_in[6];  const float* bk0 = (const float*)d_in[7];
    const float* Wq0 = (const float*)d_in[8];  const float* bq0 = (const float*)d_in[9];
    const float* Wv0 = (const float*)d_in[10]; const float* bv0 = (const float*)d_in[11];
    const float* Wa0 = (const float*)d_in[12]; const float* ba0 = (const float*)d_in[13];
    const float* Wk1 = (const float*)d_in[14]; const float* bk1 = (const float*)d_in[15];
    const float* Wq1 = (const float*)d_in[16]; const float* bq1 = (const float*)d_in[17];
    const float* Wv1 = (const float*)d_in[18]; const float* bv1 = (const float*)d_in[19];
    const float* Wa1 = (const float*)d_in[20]; const float* ba1 = (const float*)d_in[21];
    const float* rel_att = (const float*)d_in[22];
    const float* rel_msg = (const float*)d_in[23];
    const float* rel_pri = (const float*)d_in[24];
    const float* skipv   = (const float*)d_in[25];
    float* out = (float*)d_out;

    char* p = (char*)d_ws;
    auto alloc = [&](size_t bytes) -> char* {
        char* r = p;
        p += (bytes + 255) & ~(size_t)255;
        return r;
    };
    ushort_t* hp_pad = (ushort_t*)alloc((size_t)N_PAD * DIM * 2);
    ushort_t* ha_pad = (ushort_t*)alloc((size_t)N_PAD * DIM * 2);
    ushort_t* qkv_p = (ushort_t*)alloc((size_t)N_PAD * QKV_LD * 2);
    ushort_t* qkv_a = (ushort_t*)alloc((size_t)N_PAD * QKV_LD * 2);
    ushort_t* cat_p = (ushort_t*)alloc((size_t)QKV_LD * DIM * 2);
    ushort_t* cat_a = (ushort_t*)alloc((size_t)QKV_LD * DIM * 2);
    ushort_t* WaT0 = (ushort_t*)alloc(DIM * DIM * 2);
    ushort_t* WaT1 = (ushort_t*)alloc(DIM * DIM * 2);
    float* bias_p = (float*)alloc(QKV_LD * 4);
    float* bias_a = (float*)alloc(QKV_LD * 4);
    int* cnt = (int*)alloc((size_t)4 * N_NODES * 4);  // cnt[2N] then fill[2N]
    int* fill = cnt + 2 * N_NODES;
    int* row_ptr = (int*)alloc((size_t)2 * (N_NODES + 1) * 4);
    int* colarr = (int*)alloc((size_t)2 * N_EDGES * 4);

    // prep
    pad_copy2<<<dim3((N_PAD * DIM / 4 + 255) / 256, 2), 256, 0, stream>>>(h_paper, h_author, hp_pad, ha_pad);
    fuse_weights4<<<dim3(1024, 4), 256, 0, stream>>>(Wk0, bk0, Wv0, bv0, Wk1, bk1, Wv1, bv1,
                                                     rel_att, rel_msg, cat_p, cat_a, bias_p, bias_a);
    transpose4<<<dim3(256, 4), 256, 0, stream>>>(Wq0, Wq1, Wa0, Wa1, cat_p, cat_a, WaT0, WaT1);
    copy_biases<<<2, 256, 0, stream>>>(bq0, bq1, bias_p, bias_a);

    // CSR (both relations)
    hipMemsetAsync(cnt, 0, (size_t)4 * N_NODES * 4, stream);
    hist2<<<(2 * N_EDGES + 255) / 256, 256, 0, stream>>>(dst0, dst1, cnt);
    scan2<<<2, 1024, 0, stream>>>(cnt, row_ptr);
    scatter2<<<(2 * N_EDGES + 255) / 256, 256, 0, stream>>>(src0, dst0, src1, dst1, row_ptr, fill, colarr);

    // projections: qkv_p = hp @ [Wq0 | Wk0*A1 | Wv0*M1], qkv_a = ha @ [Wq1 | Wk1*A0 | Wv1*M0]
    gemm_proj<<<5640, 512, 0, stream>>>(hp_pad, ha_pad, cat_p, cat_a, bias_p, bias_a, qkv_p, qkv_a);

    // attention, both relations; t written into q columns of the dst-side qkv
    node_attn<<<dim3(N_PAD / 4, 2), 256, 0, stream>>>(qkv_p, qkv_p, qkv_a, qkv_a, row_ptr, colarr, rel_pri);

    // output GEMMs with sigmoid-skip blend
    gemm_out<<<1880, 512, 0, stream>>>(qkv_p, qkv_a, WaT0, WaT1, ba0, ba1,
                                       h_paper, h_author, skipv, out);
}

// Round 5
// 644.308 us; speedup vs baseline: 1.4186x; 1.0330x over previous
//
#include <hip/hip_runtime.h>
#include <hip/hip_bf16.h>
#include <stdint.h>

#define N_NODES 30000
#define N_PAD   30080   // 235 * 128
#define N_EDGES 100000
#define DIM     512
#define QKV_LD  1536    // packed [q | kA | vM] row stride

typedef unsigned short ushort_t;
typedef __attribute__((ext_vector_type(8))) short short8;
typedef __attribute__((ext_vector_type(8))) unsigned short ushortx8;
typedef __attribute__((ext_vector_type(4))) float floatx4;

__device__ __forceinline__ float b2f(ushort_t b) { return __uint_as_float(((unsigned)b) << 16); }
__device__ __forceinline__ ushort_t f2b(float f) {
    unsigned u = __float_as_uint(f);
    u += 0x7FFFu + ((u >> 16) & 1u);   // round-nearest-even
    return (ushort_t)(u >> 16);
}

// ---------------- pad/convert h (f32) into padded bf16 buffers ----------------
__global__ __launch_bounds__(256) void pad_copy2(const float* __restrict__ h0,
                                                 const float* __restrict__ h1,
                                                 ushort_t* __restrict__ d0,
                                                 ushort_t* __restrict__ d1) {
    const int total = N_PAD * DIM / 4;
    const int valid = N_NODES * DIM / 4;
    int idx = blockIdx.x * 256 + threadIdx.x;
    if (idx >= total) return;
    const float* s = blockIdx.y ? h1 : h0;
    ushort_t* d = blockIdx.y ? d1 : d0;
    float4 v = make_float4(0.f, 0.f, 0.f, 0.f);
    if (idx < valid) v = ((const float4*)s)[idx];
    ushort_t o[4] = {f2b(v.x), f2b(v.y), f2b(v.z), f2b(v.w)};
    ((uint2*)d)[idx] = *(const uint2*)o;
}

// ---- fold per-head relation matrix into weight, write into concatenated B^T ----
__global__ __launch_bounds__(256) void fuse_weights4(const float* __restrict__ Wk0, const float* __restrict__ bk0,
                                                     const float* __restrict__ Wv0, const float* __restrict__ bv0,
                                                     const float* __restrict__ Wk1, const float* __restrict__ bk1,
                                                     const float* __restrict__ Wv1, const float* __restrict__ bv1,
                                                     const float* __restrict__ rel_att, const float* __restrict__ rel_msg,
                                                     ushort_t* __restrict__ cat_p, ushort_t* __restrict__ cat_a,
                                                     float* __restrict__ bias_p, float* __restrict__ bias_a) {
    const float *W, *bvec, *A;
    ushort_t* outw; float* outb;
    switch (blockIdx.y) {  // rel0 folds into author-side cat, rel1 into paper-side
        case 0: W = Wk1; bvec = bk1; A = rel_att;          outw = cat_a + 512 * DIM;  outb = bias_a + 512;  break;
        case 1: W = Wv1; bvec = bv1; A = rel_msg;          outw = cat_a + 1024 * DIM; outb = bias_a + 1024; break;
        case 2: W = Wk0; bvec = bk0; A = rel_att + 32768;  outw = cat_p + 512 * DIM;  outb = bias_p + 512;  break;
        default: W = Wv0; bvec = bv0; A = rel_msg + 32768; outw = cat_p + 1024 * DIM; outb = bias_p + 1024; break;
    }
    int idx = blockIdx.x * 256 + threadIdx.x;  // 512*512
    int n = idx & 511;
    int i = idx >> 9;
    int h = n >> 6, d = n & 63;
    const float* wrow = W + i * DIM + h * 64;
    const float* acol = A + h * 4096 + d;
    float s = 0.f;
#pragma unroll 8
    for (int c = 0; c < 64; ++c) s += wrow[c] * acol[c * 64];
    outw[n * DIM + i] = f2b(s);
    if (i == 0) {
        const float* bh = bvec + h * 64;
        float sb = 0.f;
        for (int c = 0; c < 64; ++c) sb += bh[c] * acol[c * 64];
        outb[n] = sb;
    }
}

// ---- 4x 512x512 transpose f32 -> bf16 ----
__global__ __launch_bounds__(256) void transpose4(const float* w0, const float* w1,
                                                  const float* w2, const float* w3,
                                                  ushort_t* o0, ushort_t* o1,
                                                  ushort_t* o2, ushort_t* o3) {
    const float* W; ushort_t* O;
    switch (blockIdx.y) {
        case 0: W = w0; O = o0; break;
        case 1: W = w1; O = o1; break;
        case 2: W = w2; O = o2; break;
        default: W = w3; O = o3; break;
    }
    __shared__ float tile[32][33];
    int bx = blockIdx.x & 15, by = blockIdx.x >> 4;
    int tx = threadIdx.x & 31, ty = threadIdx.x >> 5;  // 32x8
#pragma unroll
    for (int r = 0; r < 32; r += 8) tile[ty + r][tx] = W[(by * 32 + ty + r) * DIM + bx * 32 + tx];
    __syncthreads();
#pragma unroll
    for (int r = 0; r < 32; r += 8) O[(bx * 32 + ty + r) * DIM + by * 32 + tx] = f2b(tile[tx][ty + r]);
}

__global__ __launch_bounds__(256) void copy_biases(const float* bq0, const float* bq1,
                                                   float* bias_p, float* bias_a) {
    int i = blockIdx.x * 256 + threadIdx.x;  // 512
    bias_p[i] = bq0[i];
    bias_a[i] = bq1[i];
}

// ---------------- CSR build (both relations in one pass) ----------------
__global__ __launch_bounds__(256) void hist2(const int* __restrict__ dst0, const int* __restrict__ dst1,
                                             int* __restrict__ cnt) {
    int e = blockIdx.x * 256 + threadIdx.x;
    if (e >= 2 * N_EDGES) return;
    int rel = e >= N_EDGES;
    int d = (rel ? dst1 : dst0)[e - rel * N_EDGES];
    atomicAdd(&cnt[rel * N_NODES + d], 1);
}

__global__ __launch_bounds__(1024) void scan2(const int* __restrict__ cnt, int* __restrict__ row_ptr) {
    int rel = blockIdx.x;
    const int* c = cnt + rel * N_NODES;
    int* rp = row_ptr + rel * (N_NODES + 1);
    __shared__ int sums[1024];
    int tid = threadIdx.x;
    int base = tid * 32;
    int loc[32];
    int s = 0;
#pragma unroll
    for (int i = 0; i < 32; ++i) {
        int idx = base + i;
        int v = (idx < N_NODES) ? c[idx] : 0;
        s += v;
        loc[i] = s;
    }
    sums[tid] = s;
    __syncthreads();
    for (int off = 1; off < 1024; off <<= 1) {
        int add = (tid >= off) ? sums[tid - off] : 0;
        __syncthreads();
        sums[tid] += add;
        __syncthreads();
    }
    int pre = (tid > 0) ? sums[tid - 1] : 0;
    if (tid == 0) rp[0] = 0;
#pragma unroll
    for (int i = 0; i < 32; ++i) {
        int idx = base + i;
        if (idx < N_NODES) rp[idx + 1] = pre + loc[i];
    }
}

__global__ __launch_bounds__(256) void scatter2(const int* __restrict__ src0, const int* __restrict__ dst0,
                                                const int* __restrict__ src1, const int* __restrict__ dst1,
                                                const int* __restrict__ row_ptr,
                                                int* __restrict__ fill,
                                                int* __restrict__ colarr) {
    int e = blockIdx.x * 256 + threadIdx.x;
    if (e >= 2 * N_EDGES) return;
    int rel = e >= N_EDGES;
    int ei = e - rel * N_EDGES;
    int s = (rel ? src1 : src0)[ei];
    int d = (rel ? dst1 : dst0)[ei];
    int pos = atomicAdd(&fill[rel * N_NODES + d], 1);
    colarr[rel * N_EDGES + row_ptr[rel * (N_NODES + 1) + d] + pos] = s;
}

// ---------------- MFMA GEMM core (128x128 tile, BK=32, 8 waves of 32x64) ----------------
// LDS XOR-swizzle (rule #21: both-sides-or-neither with global_load_lds):
// LDS dest stays linear; the GLOBAL source column slot is pre-permuted
// slot -> slot ^ ((row>>1)&3), and the fragment read applies the same XOR
// (per-lane constant (fr>>1)&3). 8-lane issue groups then cover all 32 banks.
typedef const __attribute__((address_space(1))) unsigned int gu32;
typedef __attribute__((address_space(3))) unsigned int lu32;
__device__ __forceinline__ void gload_lds16(const void* g, void* l) {
    __builtin_amdgcn_global_load_lds((gu32*)g, (lu32*)l, 16, 0, 0);
}

// projection: C[M,1536] = A[M,512] @ BT[1536,512]^T + bias, bf16 out, ldc=1536
// grid: 1D 5640 = 8 XCD chunks of 705; decode rel / m-blk / n-blk inside.
__global__ __launch_bounds__(512) void gemm_proj(const ushort_t* __restrict__ Ap, const ushort_t* __restrict__ Aa,
                                                 const ushort_t* __restrict__ Bp, const ushort_t* __restrict__ Ba,
                                                 const float* __restrict__ bias_p, const float* __restrict__ bias_a,
                                                 ushort_t* __restrict__ Cp, ushort_t* __restrict__ Ca) {
    int bid = blockIdx.x;
    int lin = (bid & 7) * 705 + (bid >> 3);   // XCD-chunked bijection (5640 = 8*705)
    int rel = lin >= 2820;
    int r = lin - rel * 2820;
    int my = r / 12, nx = r - my * 12;
    const ushort_t* A = rel ? Aa : Ap;
    const ushort_t* BT = rel ? Ba : Bp;
    const float* bias = rel ? bias_a : bias_p;
    ushort_t* C = rel ? Ca : Cp;

    __shared__ alignas(16) ushort_t As[128 * 32];
    __shared__ alignas(16) ushort_t Bs[128 * 32];
    int n0 = nx * 128, m0 = my * 128;
    int tid = threadIdx.x;
    int w = tid >> 6, l = tid & 63;
    int wr = w >> 1, wc = w & 1;          // wave covers rows [wr*32,+32), cols [wc*64,+64)
    int fr = l & 15, fq = l >> 4;
    floatx4 acc[2][4] = {};
    int aXor = (fr >> 1) & 3;             // read-side XOR, constant per lane
    const ushort_t* aF = &As[(wr * 32 + fr) * 32 + (fq ^ aXor) * 8];
    const ushort_t* bF = &Bs[(wc * 64 + fr) * 32 + (fq ^ aXor) * 8];
    // staging map: thread t stages granules g and g+256 (rows srow, srow+64);
    // global source slot pre-permuted to match the read-side XOR.
    int g = tid & 255;
    int srow = g >> 2;
    int sc0 = (((g & 3) ^ ((srow >> 1) & 3))) * 8;
    const ushort_t* gsrc0 = (tid < 256) ? (A + (size_t)(m0 + srow) * DIM + sc0)
                                        : (BT + (size_t)(n0 + srow) * DIM + sc0);
    const ushort_t* gsrc1 = gsrc0 + (size_t)64 * DIM;
    char* ldst = (tid < 256) ? ((char*)As + g * 16) : ((char*)Bs + g * 16);

#pragma unroll 1
    for (int kt = 0; kt < 16; ++kt) {
        int k0 = kt * 32;
        if (kt) __syncthreads();
        gload_lds16(gsrc0 + k0, ldst);
        gload_lds16(gsrc1 + k0, ldst + 4096);
        __syncthreads();
        short8 af[2], bf[4];
#pragma unroll
        for (int i = 0; i < 2; ++i) af[i] = *(const short8*)(aF + i * 16 * 32);
#pragma unroll
        for (int j = 0; j < 4; ++j) bf[j] = *(const short8*)(bF + j * 16 * 32);
#pragma unroll
        for (int i = 0; i < 2; ++i)
#pragma unroll
            for (int j = 0; j < 4; ++j)
                acc[i][j] = __builtin_amdgcn_mfma_f32_16x16x32_bf16(af[i], bf[j], acc[i][j], 0, 0, 0);
    }
#pragma unroll
    for (int i = 0; i < 2; ++i)
#pragma unroll
        for (int j = 0; j < 4; ++j) {
            int col = n0 + wc * 64 + j * 16 + fr;
            float bc = bias[col];
#pragma unroll
            for (int rr = 0; rr < 4; ++rr) {
                int grow = m0 + wr * 32 + i * 16 + fq * 4 + rr;
                C[(size_t)grow * QKV_LD + col] = f2b(acc[i][j][rr] + bc);
            }
        }
}

// out: C[M,512] = T[M,512](lda=1536) @ WaT^T + ba, sigmoid-skip blend vs bf16 residual
// grid: 1D 1880 = 8 XCD chunks of 235.
__global__ __launch_bounds__(512) void gemm_out(const ushort_t* __restrict__ Tp, const ushort_t* __restrict__ Ta,
                                                const ushort_t* __restrict__ Wp, const ushort_t* __restrict__ Wa,
                                                const float* __restrict__ ba0, const float* __restrict__ ba1,
                                                const ushort_t* __restrict__ hp, const ushort_t* __restrict__ ha,
                                                const float* __restrict__ skipv, float* __restrict__ out) {
    int bid = blockIdx.x;
    int lin = (bid & 7) * 235 + (bid >> 3);   // XCD-chunked bijection (1880 = 8*235)
    int rel = lin >= 940;
    int r = lin - rel * 940;
    int my = r >> 2, nx = r & 3;
    const ushort_t* A = rel ? Ta : Tp;
    const ushort_t* BT = rel ? Wa : Wp;
    const float* bias = rel ? ba1 : ba0;
    const ushort_t* Hres = rel ? ha : hp;   // bf16 padded residual
    float* C = out + (size_t)rel * N_NODES * DIM;

    __shared__ alignas(16) ushort_t As[128 * 32];
    __shared__ alignas(16) ushort_t Bs[128 * 32];
    int n0 = nx * 128, m0 = my * 128;
    int tid = threadIdx.x;
    int w = tid >> 6, l = tid & 63;
    int wr = w >> 1, wc = w & 1;
    int fr = l & 15, fq = l >> 4;
    floatx4 acc[2][4] = {};
    int aXor = (fr >> 1) & 3;
    const ushort_t* aF = &As[(wr * 32 + fr) * 32 + (fq ^ aXor) * 8];
    const ushort_t* bF = &Bs[(wc * 64 + fr) * 32 + (fq ^ aXor) * 8];
    int g = tid & 255;
    int srow = g >> 2;
    int sc0 = (((g & 3) ^ ((srow >> 1) & 3))) * 8;
    const ushort_t* gsrc0 = (tid < 256) ? (A + (size_t)(m0 + srow) * QKV_LD + sc0)
                                        : (BT + (size_t)(n0 + srow) * DIM + sc0);
    const ushort_t* gsrc1 = gsrc0 + (size_t)64 * ((tid < 256) ? QKV_LD : DIM);
    char* ldst = (tid < 256) ? ((char*)As + g * 16) : ((char*)Bs + g * 16);

#pragma unroll 1
    for (int kt = 0; kt < 16; ++kt) {
        int k0 = kt * 32;
        if (kt) __syncthreads();
        gload_lds16(gsrc0 + k0, ldst);
        gload_lds16(gsrc1 + k0, ldst + 4096);
        __syncthreads();
        short8 af[2], bf[4];
#pragma unroll
        for (int i = 0; i < 2; ++i) af[i] = *(const short8*)(aF + i * 16 * 32);
#pragma unroll
        for (int j = 0; j < 4; ++j) bf[j] = *(const short8*)(bF + j * 16 * 32);
#pragma unroll
        for (int i = 0; i < 2; ++i)
#pragma unroll
            for (int j = 0; j < 4; ++j)
                acc[i][j] = __builtin_amdgcn_mfma_f32_16x16x32_bf16(af[i], bf[j], acc[i][j], 0, 0, 0);
    }
    float sk = skipv[rel];
    float alpha = 1.f / (1.f + __expf(-sk));
    float onem = 1.f - alpha;
#pragma unroll
    for (int i = 0; i < 2; ++i)
#pragma unroll
        for (int j = 0; j < 4; ++j) {
            int col = n0 + wc * 64 + j * 16 + fr;
            float bc = bias[col];
#pragma unroll
            for (int rr = 0; rr < 4; ++rr) {
                int grow = m0 + wr * 32 + i * 16 + fq * 4 + rr;
                if (grow < N_NODES) {
                    float v = acc[i][j][rr] + bc;
                    float hres = b2f(Hres[(size_t)grow * DIM + col]);
                    C[(size_t)grow * DIM + col] = v * alpha + hres * onem;
                }
            }
        }
}

// ------- per-node online-softmax aggregation: one wave = one node, all 8 heads -------
__global__ __launch_bounds__(256) void node_attn(const ushort_t* __restrict__ qkv_p,
                                                 ushort_t* __restrict__ qkv_p_mut,
                                                 const ushort_t* __restrict__ qkv_a,
                                                 ushort_t* __restrict__ qkv_a_mut,
                                                 const int* __restrict__ row_ptr,
                                                 const int* __restrict__ colarr,
                                                 const float* __restrict__ rel_pri) {
    int rel = blockIdx.y;
    const ushort_t* qkv_dst = rel ? qkv_a : qkv_p;
    ushort_t* t_out = rel ? qkv_a_mut : qkv_p_mut;
    const ushort_t* qkv_src = rel ? qkv_p : qkv_a;
    const int* rp = row_ptr + rel * (N_NODES + 1);
    const int* col = colarr + rel * N_EDGES;
    const float* pri = rel_pri + rel * 8;

    int w = threadIdx.x >> 6, l = threadIdx.x & 63;
    int n = blockIdx.x * 4 + w;  // < N_PAD
    float prih = pri[l >> 3] * 0.125f;  // pri[h] / sqrt(64)

    size_t qoff = (size_t)n * QKV_LD + l * 8;
    ushortx8 qr = *(const ushortx8*)(qkv_dst + qoff);
    float qd[8];
#pragma unroll
    for (int i = 0; i < 8; ++i) qd[i] = b2f(qr[i]);

    int lo = 0, hi = 0;
    if (n < N_NODES) { lo = rp[n]; hi = rp[n + 1]; }

    float m = -3.0e38f, s = 0.f;
    float acc[8] = {};
    int j = lo;
    ushortx8 kr, vr;
    if (j < hi) {
        int sn = col[j];
        const ushort_t* kb = qkv_src + (size_t)sn * QKV_LD + 512 + l * 8;
        kr = *(const ushortx8*)kb;
        vr = *(const ushortx8*)(kb + 512);
    }
    while (j < hi) {
        ushortx8 kc = kr, vc = vr;
        ++j;
        if (j < hi) {  // one-edge lookahead
            int sn = col[j];
            const ushort_t* kb = qkv_src + (size_t)sn * QKV_LD + 512 + l * 8;
            kr = *(const ushortx8*)kb;
            vr = *(const ushortx8*)(kb + 512);
        }
        float dot = 0.f;
#pragma unroll
        for (int i = 0; i < 8; ++i) dot += qd[i] * b2f(kc[i]);
        dot += __shfl_xor(dot, 1);
        dot += __shfl_xor(dot, 2);
        dot += __shfl_xor(dot, 4);   // full head-dot, replicated across 8-lane group
        float att = dot * prih;
        float mn = fmaxf(m, att);
        float e0 = __expf(m - mn);
        float e1 = __expf(att - mn);
        s = s * e0 + e1;
#pragma unroll
        for (int i = 0; i < 8; ++i) acc[i] = acc[i] * e0 + e1 * b2f(vc[i]);
        m = mn;
    }
    float inv = (hi > lo) ? 1.f / s : 0.f;
    ushortx8 o;
#pragma unroll
    for (int i = 0; i < 8; ++i) o[i] = f2b(acc[i] * inv);
    *(ushortx8*)(t_out + qoff) = o;  // overwrite q columns (disjoint from kA/vM reads)
}

// ---------------- host launch ----------------
extern "C" void kernel_launch(void* const* d_in, const int* in_sizes, int n_in,
                              void* d_out, int out_size, void* d_ws, size_t ws_size,
                              hipStream_t stream) {
    (void)in_sizes; (void)n_in; (void)out_size; (void)ws_size;
    const float* h_paper  = (const float*)d_in[0];
    const float* h_author = (const float*)d_in[1];
    const int* src0 = (const int*)d_in[2];
    const int* dst0 = (const int*)d_in[3];
    const int* src1 = (const int*)d_in[4];
    const int* dst1 = (const int*)d_in[5];
    const float* Wk0 = (const float*)d_in[6];  const float* bk0 = (const float*)d_in[7];
    const float* Wq0 = (const float*)d_in[8];  const float* bq0 = (const float*)d_in[9];
    const float* Wv0 = (const float*)d_in[10]; const float* bv0 = (const float*)d_in[11];
    const float* Wa0 = (const float*)d_in[12]; const float* ba0 = (const float*)d_in[13];
    const float* Wk1 = (const float*)d_in[14]; const float* bk1 = (const float*)d_in[15];
    const float* Wq1 = (const float*)d_in[16]; const float* bq1 = (const float*)d_in[17];
    const float* Wv1 = (const float*)d_in[18]; const float* bv1 = (const float*)d_in[19];
    const float* Wa1 = (const float*)d_in[20]; const float* ba1 = (const float*)d_in[21];
    const float* rel_att = (const float*)d_in[22];
    const float* rel_msg = (const float*)d_in[23];
    const float* rel_pri = (const float*)d_in[24];
    const float* skipv   = (const float*)d_in[25];
    float* out = (float*)d_out;

    char* p = (char*)d_ws;
    auto alloc = [&](size_t bytes) -> char* {
        char* r = p;
        p += (bytes + 255) & ~(size_t)255;
        return r;
    };
    ushort_t* hp_pad = (ushort_t*)alloc((size_t)N_PAD * DIM * 2);
    ushort_t* ha_pad = (ushort_t*)alloc((size_t)N_PAD * DIM * 2);
    ushort_t* qkv_p = (ushort_t*)alloc((size_t)N_PAD * QKV_LD * 2);
    ushort_t* qkv_a = (ushort_t*)alloc((size_t)N_PAD * QKV_LD * 2);
    ushort_t* cat_p = (ushort_t*)alloc((size_t)QKV_LD * DIM * 2);
    ushort_t* cat_a = (ushort_t*)alloc((size_t)QKV_LD * DIM * 2);
    ushort_t* WaT0 = (ushort_t*)alloc(DIM * DIM * 2);
    ushort_t* WaT1 = (ushort_t*)alloc(DIM * DIM * 2);
    float* bias_p = (float*)alloc(QKV_LD * 4);
    float* bias_a = (float*)alloc(QKV_LD * 4);
    int* cnt = (int*)alloc((size_t)4 * N_NODES * 4);  // cnt[2N] then fill[2N]
    int* fill = cnt + 2 * N_NODES;
    int* row_ptr = (int*)alloc((size_t)2 * (N_NODES + 1) * 4);
    int* colarr = (int*)alloc((size_t)2 * N_EDGES * 4);

    // prep
    pad_copy2<<<dim3((N_PAD * DIM / 4 + 255) / 256, 2), 256, 0, stream>>>(h_paper, h_author, hp_pad, ha_pad);
    fuse_weights4<<<dim3(1024, 4), 256, 0, stream>>>(Wk0, bk0, Wv0, bv0, Wk1, bk1, Wv1, bv1,
                                                     rel_att, rel_msg, cat_p, cat_a, bias_p, bias_a);
    transpose4<<<dim3(256, 4), 256, 0, stream>>>(Wq0, Wq1, Wa0, Wa1, cat_p, cat_a, WaT0, WaT1);
    copy_biases<<<2, 256, 0, stream>>>(bq0, bq1, bias_p, bias_a);

    // CSR (both relations)
    hipMemsetAsync(cnt, 0, (size_t)4 * N_NODES * 4, stream);
    hist2<<<(2 * N_EDGES + 255) / 256, 256, 0, stream>>>(dst0, dst1, cnt);
    scan2<<<2, 1024, 0, stream>>>(cnt, row_ptr);
    scatter2<<<(2 * N_EDGES + 255) / 256, 256, 0, stream>>>(src0, dst0, src1, dst1, row_ptr, fill, colarr);

    // projections: qkv_p = hp @ [Wq0 | Wk0*A1 | Wv0*M1], qkv_a = ha @ [Wq1 | Wk1*A0 | Wv1*M0]
    gemm_proj<<<5640, 512, 0, stream>>>(hp_pad, ha_pad, cat_p, cat_a, bias_p, bias_a, qkv_p, qkv_a);

    // attention, both relations; t written into q columns of the dst-side qkv
    node_attn<<<dim3(N_PAD / 4, 2), 256, 0, stream>>>(qkv_p, qkv_p, qkv_a, qkv_a, row_ptr, colarr, rel_pri);

    // output GEMMs with sigmoid-skip blend (bf16 residual from hp_pad/ha_pad)
    gemm_out<<<1880, 512, 0, stream>>>(qkv_p, qkv_a, WaT0, WaT1, ba0, ba1,
                                       hp_pad, ha_pad, skipv, out);
}

// Round 6
// 637.304 us; speedup vs baseline: 1.4342x; 1.0110x over previous
//
#include <hip/hip_runtime.h>
#include <hip/hip_bf16.h>
#include <stdint.h>

#define N_NODES 30000
#define N_PAD   30080   // 235 * 128
#define N_EDGES 100000
#define DIM     512
#define QKV_LD  1536    // packed [q | kA | vM] row stride

typedef unsigned short ushort_t;
typedef __attribute__((ext_vector_type(8))) short short8;
typedef __attribute__((ext_vector_type(8))) unsigned short ushortx8;
typedef __attribute__((ext_vector_type(4))) float floatx4;

__device__ __forceinline__ float b2f(ushort_t b) { return __uint_as_float(((unsigned)b) << 16); }
__device__ __forceinline__ ushort_t f2b(float f) {
    unsigned u = __float_as_uint(f);
    u += 0x7FFFu + ((u >> 16) & 1u);   // round-nearest-even
    return (ushort_t)(u >> 16);
}

// ---------------- pad/convert h (f32) into padded bf16 buffers ----------------
__global__ __launch_bounds__(256) void pad_copy2(const float* __restrict__ h0,
                                                 const float* __restrict__ h1,
                                                 ushort_t* __restrict__ d0,
                                                 ushort_t* __restrict__ d1) {
    const int total = N_PAD * DIM / 4;
    const int valid = N_NODES * DIM / 4;
    int idx = blockIdx.x * 256 + threadIdx.x;
    if (idx >= total) return;
    const float* s = blockIdx.y ? h1 : h0;
    ushort_t* d = blockIdx.y ? d1 : d0;
    float4 v = make_float4(0.f, 0.f, 0.f, 0.f);
    if (idx < valid) v = ((const float4*)s)[idx];
    ushort_t o[4] = {f2b(v.x), f2b(v.y), f2b(v.z), f2b(v.w)};
    ((uint2*)d)[idx] = *(const uint2*)o;
}

// ---- fold per-head relation matrix into weight, write into concatenated B^T ----
__global__ __launch_bounds__(256) void fuse_weights4(const float* __restrict__ Wk0, const float* __restrict__ bk0,
                                                     const float* __restrict__ Wv0, const float* __restrict__ bv0,
                                                     const float* __restrict__ Wk1, const float* __restrict__ bk1,
                                                     const float* __restrict__ Wv1, const float* __restrict__ bv1,
                                                     const float* __restrict__ rel_att, const float* __restrict__ rel_msg,
                                                     ushort_t* __restrict__ cat_p, ushort_t* __restrict__ cat_a,
                                                     float* __restrict__ bias_p, float* __restrict__ bias_a) {
    const float *W, *bvec, *A;
    ushort_t* outw; float* outb;
    switch (blockIdx.y) {  // rel0 folds into author-side cat, rel1 into paper-side
        case 0: W = Wk1; bvec = bk1; A = rel_att;          outw = cat_a + 512 * DIM;  outb = bias_a + 512;  break;
        case 1: W = Wv1; bvec = bv1; A = rel_msg;          outw = cat_a + 1024 * DIM; outb = bias_a + 1024; break;
        case 2: W = Wk0; bvec = bk0; A = rel_att + 32768;  outw = cat_p + 512 * DIM;  outb = bias_p + 512;  break;
        default: W = Wv0; bvec = bv0; A = rel_msg + 32768; outw = cat_p + 1024 * DIM; outb = bias_p + 1024; break;
    }
    int idx = blockIdx.x * 256 + threadIdx.x;  // 512*512
    int n = idx & 511;
    int i = idx >> 9;
    int h = n >> 6, d = n & 63;
    const float* wrow = W + i * DIM + h * 64;
    const float* acol = A + h * 4096 + d;
    float s = 0.f;
#pragma unroll 8
    for (int c = 0; c < 64; ++c) s += wrow[c] * acol[c * 64];
    outw[n * DIM + i] = f2b(s);
    if (i == 0) {
        const float* bh = bvec + h * 64;
        float sb = 0.f;
        for (int c = 0; c < 64; ++c) sb += bh[c] * acol[c * 64];
        outb[n] = sb;
    }
}

// ---- 4x 512x512 transpose f32 -> bf16 ----
__global__ __launch_bounds__(256) void transpose4(const float* w0, const float* w1,
                                                  const float* w2, const float* w3,
                                                  ushort_t* o0, ushort_t* o1,
                                                  ushort_t* o2, ushort_t* o3) {
    const float* W; ushort_t* O;
    switch (blockIdx.y) {
        case 0: W = w0; O = o0; break;
        case 1: W = w1; O = o1; break;
        case 2: W = w2; O = o2; break;
        default: W = w3; O = o3; break;
    }
    __shared__ float tile[32][33];
    int bx = blockIdx.x & 15, by = blockIdx.x >> 4;
    int tx = threadIdx.x & 31, ty = threadIdx.x >> 5;  // 32x8
#pragma unroll
    for (int r = 0; r < 32; r += 8) tile[ty + r][tx] = W[(by * 32 + ty + r) * DIM + bx * 32 + tx];
    __syncthreads();
#pragma unroll
    for (int r = 0; r < 32; r += 8) O[(bx * 32 + ty + r) * DIM + by * 32 + tx] = f2b(tile[tx][ty + r]);
}

__global__ __launch_bounds__(256) void copy_biases(const float* bq0, const float* bq1,
                                                   float* bias_p, float* bias_a) {
    int i = blockIdx.x * 256 + threadIdx.x;  // 512
    bias_p[i] = bq0[i];
    bias_a[i] = bq1[i];
}

// ---------------- CSR build (both relations in one pass) ----------------
__global__ __launch_bounds__(256) void hist2(const int* __restrict__ dst0, const int* __restrict__ dst1,
                                             int* __restrict__ cnt) {
    int e = blockIdx.x * 256 + threadIdx.x;
    if (e >= 2 * N_EDGES) return;
    int rel = e >= N_EDGES;
    int d = (rel ? dst1 : dst0)[e - rel * N_EDGES];
    atomicAdd(&cnt[rel * N_NODES + d], 1);
}

__global__ __launch_bounds__(1024) void scan2(const int* __restrict__ cnt, int* __restrict__ row_ptr) {
    int rel = blockIdx.x;
    const int* c = cnt + rel * N_NODES;
    int* rp = row_ptr + rel * (N_NODES + 1);
    __shared__ int sums[1024];
    int tid = threadIdx.x;
    int base = tid * 32;
    int loc[32];
    int s = 0;
#pragma unroll
    for (int i = 0; i < 32; ++i) {
        int idx = base + i;
        int v = (idx < N_NODES) ? c[idx] : 0;
        s += v;
        loc[i] = s;
    }
    sums[tid] = s;
    __syncthreads();
    for (int off = 1; off < 1024; off <<= 1) {
        int add = (tid >= off) ? sums[tid - off] : 0;
        __syncthreads();
        sums[tid] += add;
        __syncthreads();
    }
    int pre = (tid > 0) ? sums[tid - 1] : 0;
    if (tid == 0) rp[0] = 0;
#pragma unroll
    for (int i = 0; i < 32; ++i) {
        int idx = base + i;
        if (idx < N_NODES) rp[idx + 1] = pre + loc[i];
    }
}

__global__ __launch_bounds__(256) void scatter2(const int* __restrict__ src0, const int* __restrict__ dst0,
                                                const int* __restrict__ src1, const int* __restrict__ dst1,
                                                const int* __restrict__ row_ptr,
                                                int* __restrict__ fill,
                                                int* __restrict__ colarr) {
    int e = blockIdx.x * 256 + threadIdx.x;
    if (e >= 2 * N_EDGES) return;
    int rel = e >= N_EDGES;
    int ei = e - rel * N_EDGES;
    int s = (rel ? src1 : src0)[ei];
    int d = (rel ? dst1 : dst0)[ei];
    int pos = atomicAdd(&fill[rel * N_NODES + d], 1);
    colarr[rel * N_EDGES + row_ptr[rel * (N_NODES + 1) + d] + pos] = s;
}

// ---------------- MFMA GEMM core (128x128 tile, BK=64, 8 waves of 32x64) ----------------
// BK=64 halves the K-step count (8 steps) -> halves barrier-drain events, the
// 2-phase structure's dominant cost (R5: conflict removal gained only 3%).
// LDS 32KB/block; 4 blocks/CU still fit (128/160KB).
// Swizzle for 128B rows: LDS slot s holds global slot s^(row&7); read-side key
// fr&7 (rows step by 16/32 -> invariant). Residual 8-way conflict accepted.
typedef const __attribute__((address_space(1))) unsigned int gu32;
typedef __attribute__((address_space(3))) unsigned int lu32;
__device__ __forceinline__ void gload_lds16(const void* g, void* l) {
    __builtin_amdgcn_global_load_lds((gu32*)g, (lu32*)l, 16, 0, 0);
}

// projection: C[M,1536] = A[M,512] @ BT[1536,512]^T + bias, bf16 out, ldc=1536
// grid: 1D 5640 = 8 XCD chunks of 705; decode rel / m-blk / n-blk inside.
__global__ __launch_bounds__(512) void gemm_proj(const ushort_t* __restrict__ Ap, const ushort_t* __restrict__ Aa,
                                                 const ushort_t* __restrict__ Bp, const ushort_t* __restrict__ Ba,
                                                 const float* __restrict__ bias_p, const float* __restrict__ bias_a,
                                                 ushort_t* __restrict__ Cp, ushort_t* __restrict__ Ca) {
    int bid = blockIdx.x;
    int lin = (bid & 7) * 705 + (bid >> 3);   // XCD-chunked bijection (5640 = 8*705)
    int rel = lin >= 2820;
    int r = lin - rel * 2820;
    int my = r / 12, nx = r - my * 12;
    const ushort_t* A = rel ? Aa : Ap;
    const ushort_t* BT = rel ? Ba : Bp;
    const float* bias = rel ? bias_a : bias_p;
    ushort_t* C = rel ? Ca : Cp;

    __shared__ alignas(16) ushort_t As[128 * 64];
    __shared__ alignas(16) ushort_t Bs[128 * 64];
    int n0 = nx * 128, m0 = my * 128;
    int tid = threadIdx.x;
    int w = tid >> 6, l = tid & 63;
    int wr = w >> 1, wc = w & 1;          // wave covers rows [wr*32,+32), cols [wc*64,+64)
    int fr = l & 15, fq = l >> 4;
    floatx4 acc[2][4] = {};
    int s0 = fq ^ (fr & 7);               // read slot for kk=0; kk=1 is s0^4
    const ushort_t* aF0 = &As[(wr * 32 + fr) * 64 + s0 * 8];
    const ushort_t* aF1 = &As[(wr * 32 + fr) * 64 + (s0 ^ 4) * 8];
    const ushort_t* bF0 = &Bs[(wc * 64 + fr) * 64 + s0 * 8];
    const ushort_t* bF1 = &Bs[(wc * 64 + fr) * 64 + (s0 ^ 4) * 8];
    // staging: thread tq in [0,256) handles matrix half, granules tq+256q (q=0..3)
    // granule G: row=G>>3, lds slot=G&7, global slot pre-swizzled ^(row&7).
    int tq = tid & 255;
    int r0 = tq >> 3;
    int ss = ((tq & 7) ^ (r0 & 7)) * 8;
    const ushort_t* gsrc = (tid < 256) ? (A + (size_t)(m0 + r0) * DIM + ss)
                                       : (BT + (size_t)(n0 + r0) * DIM + ss);
    char* ldst = (tid < 256) ? ((char*)As + tq * 16) : ((char*)Bs + tq * 16);

#pragma unroll 1
    for (int kt = 0; kt < 8; ++kt) {
        int k0 = kt * 64;
        if (kt) __syncthreads();
#pragma unroll
        for (int q = 0; q < 4; ++q)
            gload_lds16(gsrc + k0 + (size_t)q * 32 * DIM, ldst + q * 4096);
        __syncthreads();
        short8 af[2][2], bf[2][4];
#pragma unroll
        for (int i = 0; i < 2; ++i) {
            af[0][i] = *(const short8*)(aF0 + i * 16 * 64);
            af[1][i] = *(const short8*)(aF1 + i * 16 * 64);
        }
#pragma unroll
        for (int j = 0; j < 4; ++j) {
            bf[0][j] = *(const short8*)(bF0 + j * 16 * 64);
            bf[1][j] = *(const short8*)(bF1 + j * 16 * 64);
        }
#pragma unroll
        for (int kk = 0; kk < 2; ++kk)
#pragma unroll
            for (int i = 0; i < 2; ++i)
#pragma unroll
                for (int j = 0; j < 4; ++j)
                    acc[i][j] = __builtin_amdgcn_mfma_f32_16x16x32_bf16(af[kk][i], bf[kk][j], acc[i][j], 0, 0, 0);
    }
#pragma unroll
    for (int i = 0; i < 2; ++i)
#pragma unroll
        for (int j = 0; j < 4; ++j) {
            int col = n0 + wc * 64 + j * 16 + fr;
            float bc = bias[col];
#pragma unroll
            for (int rr = 0; rr < 4; ++rr) {
                int grow = m0 + wr * 32 + i * 16 + fq * 4 + rr;
                C[(size_t)grow * QKV_LD + col] = f2b(acc[i][j][rr] + bc);
            }
        }
}

// out: C[M,512] = T[M,512](lda=1536) @ WaT^T + ba, sigmoid-skip blend vs bf16 residual
// grid: 1D 1880 = 8 XCD chunks of 235.
__global__ __launch_bounds__(512) void gemm_out(const ushort_t* __restrict__ Tp, const ushort_t* __restrict__ Ta,
                                                const ushort_t* __restrict__ Wp, const ushort_t* __restrict__ Wa,
                                                const float* __restrict__ ba0, const float* __restrict__ ba1,
                                                const ushort_t* __restrict__ hp, const ushort_t* __restrict__ ha,
                                                const float* __restrict__ skipv, float* __restrict__ out) {
    int bid = blockIdx.x;
    int lin = (bid & 7) * 235 + (bid >> 3);   // XCD-chunked bijection (1880 = 8*235)
    int rel = lin >= 940;
    int r = lin - rel * 940;
    int my = r >> 2, nx = r & 3;
    const ushort_t* A = rel ? Ta : Tp;
    const ushort_t* BT = rel ? Wa : Wp;
    const float* bias = rel ? ba1 : ba0;
    const ushort_t* Hres = rel ? ha : hp;   // bf16 padded residual
    float* C = out + (size_t)rel * N_NODES * DIM;

    __shared__ alignas(16) ushort_t As[128 * 64];
    __shared__ alignas(16) ushort_t Bs[128 * 64];
    int n0 = nx * 128, m0 = my * 128;
    int tid = threadIdx.x;
    int w = tid >> 6, l = tid & 63;
    int wr = w >> 1, wc = w & 1;
    int fr = l & 15, fq = l >> 4;
    floatx4 acc[2][4] = {};
    int s0 = fq ^ (fr & 7);
    const ushort_t* aF0 = &As[(wr * 32 + fr) * 64 + s0 * 8];
    const ushort_t* aF1 = &As[(wr * 32 + fr) * 64 + (s0 ^ 4) * 8];
    const ushort_t* bF0 = &Bs[(wc * 64 + fr) * 64 + s0 * 8];
    const ushort_t* bF1 = &Bs[(wc * 64 + fr) * 64 + (s0 ^ 4) * 8];
    int tq = tid & 255;
    int r0 = tq >> 3;
    int ss = ((tq & 7) ^ (r0 & 7)) * 8;
    size_t lda = (tid < 256) ? (size_t)QKV_LD : (size_t)DIM;
    const ushort_t* gsrc = (tid < 256) ? (A + (size_t)(m0 + r0) * QKV_LD + ss)
                                       : (BT + (size_t)(n0 + r0) * DIM + ss);
    char* ldst = (tid < 256) ? ((char*)As + tq * 16) : ((char*)Bs + tq * 16);

#pragma unroll 1
    for (int kt = 0; kt < 8; ++kt) {
        int k0 = kt * 64;
        if (kt) __syncthreads();
#pragma unroll
        for (int q = 0; q < 4; ++q)
            gload_lds16(gsrc + k0 + (size_t)q * 32 * lda, ldst + q * 4096);
        __syncthreads();
        short8 af[2][2], bf[2][4];
#pragma unroll
        for (int i = 0; i < 2; ++i) {
            af[0][i] = *(const short8*)(aF0 + i * 16 * 64);
            af[1][i] = *(const short8*)(aF1 + i * 16 * 64);
        }
#pragma unroll
        for (int j = 0; j < 4; ++j) {
            bf[0][j] = *(const short8*)(bF0 + j * 16 * 64);
            bf[1][j] = *(const short8*)(bF1 + j * 16 * 64);
        }
#pragma unroll
        for (int kk = 0; kk < 2; ++kk)
#pragma unroll
            for (int i = 0; i < 2; ++i)
#pragma unroll
                for (int j = 0; j < 4; ++j)
                    acc[i][j] = __builtin_amdgcn_mfma_f32_16x16x32_bf16(af[kk][i], bf[kk][j], acc[i][j], 0, 0, 0);
    }
    float sk = skipv[rel];
    float alpha = 1.f / (1.f + __expf(-sk));
    float onem = 1.f - alpha;
#pragma unroll
    for (int i = 0; i < 2; ++i)
#pragma unroll
        for (int j = 0; j < 4; ++j) {
            int col = n0 + wc * 64 + j * 16 + fr;
            float bc = bias[col];
#pragma unroll
            for (int rr = 0; rr < 4; ++rr) {
                int grow = m0 + wr * 32 + i * 16 + fq * 4 + rr;
                if (grow < N_NODES) {
                    float v = acc[i][j][rr] + bc;
                    float hres = b2f(Hres[(size_t)grow * DIM + col]);
                    C[(size_t)grow * DIM + col] = v * alpha + hres * onem;
                }
            }
        }
}

// ------- per-node online-softmax aggregation: one wave = one node, all 8 heads -------
// Two independent online-softmax chains (even/odd edges) halve the loop-carried
// dependency chain and double outstanding K/V loads; exact merge at the end.
__global__ __launch_bounds__(256) void node_attn(const ushort_t* __restrict__ qkv_p,
                                                 ushort_t* __restrict__ qkv_p_mut,
                                                 const ushort_t* __restrict__ qkv_a,
                                                 ushort_t* __restrict__ qkv_a_mut,
                                                 const int* __restrict__ row_ptr,
                                                 const int* __restrict__ colarr,
                                                 const float* __restrict__ rel_pri) {
    int rel = blockIdx.y;
    const ushort_t* qkv_dst = rel ? qkv_a : qkv_p;
    ushort_t* t_out = rel ? qkv_a_mut : qkv_p_mut;
    const ushort_t* qkv_src = rel ? qkv_p : qkv_a;
    const int* rp = row_ptr + rel * (N_NODES + 1);
    const int* col = colarr + rel * N_EDGES;
    const float* pri = rel_pri + rel * 8;

    int w = threadIdx.x >> 6, l = threadIdx.x & 63;
    int n = blockIdx.x * 4 + w;  // < N_PAD
    float prih = pri[l >> 3] * 0.125f;  // pri[h] / sqrt(64)

    size_t qoff = (size_t)n * QKV_LD + l * 8;
    ushortx8 qr = *(const ushortx8*)(qkv_dst + qoff);
    float qd[8];
#pragma unroll
    for (int i = 0; i < 8; ++i) qd[i] = b2f(qr[i]);

    int lo = 0, hi = 0;
    if (n < N_NODES) { lo = rp[n]; hi = rp[n + 1]; }

    float m0v = -3.0e38f, s0v = 0.f;
    float m1v = -3.0e38f, s1v = 0.f;
    float acc0[8] = {}, acc1[8] = {};
    int j = lo;
    while (j + 1 < hi) {
        int sn0 = col[j], sn1 = col[j + 1];
        const ushort_t* kb0 = qkv_src + (size_t)sn0 * QKV_LD + 512 + l * 8;
        const ushort_t* kb1 = qkv_src + (size_t)sn1 * QKV_LD + 512 + l * 8;
        ushortx8 kc0 = *(const ushortx8*)kb0;
        ushortx8 vc0 = *(const ushortx8*)(kb0 + 512);
        ushortx8 kc1 = *(const ushortx8*)kb1;
        ushortx8 vc1 = *(const ushortx8*)(kb1 + 512);
        float d0 = 0.f, d1 = 0.f;
#pragma unroll
        for (int i = 0; i < 8; ++i) { d0 += qd[i] * b2f(kc0[i]); d1 += qd[i] * b2f(kc1[i]); }
        d0 += __shfl_xor(d0, 1); d1 += __shfl_xor(d1, 1);
        d0 += __shfl_xor(d0, 2); d1 += __shfl_xor(d1, 2);
        d0 += __shfl_xor(d0, 4); d1 += __shfl_xor(d1, 4);
        float a0 = d0 * prih, a1 = d1 * prih;
        float mn0 = fmaxf(m0v, a0);
        float e00 = __expf(m0v - mn0), e01 = __expf(a0 - mn0);
        float mn1 = fmaxf(m1v, a1);
        float e10 = __expf(m1v - mn1), e11 = __expf(a1 - mn1);
        s0v = s0v * e00 + e01;
        s1v = s1v * e10 + e11;
#pragma unroll
        for (int i = 0; i < 8; ++i) {
            acc0[i] = acc0[i] * e00 + e01 * b2f(vc0[i]);
            acc1[i] = acc1[i] * e10 + e11 * b2f(vc1[i]);
        }
        m0v = mn0; m1v = mn1;
        j += 2;
    }
    if (j < hi) {   // odd remainder -> chain 0
        int sn = col[j];
        const ushort_t* kb = qkv_src + (size_t)sn * QKV_LD + 512 + l * 8;
        ushortx8 kc = *(const ushortx8*)kb;
        ushortx8 vc = *(const ushortx8*)(kb + 512);
        float d0 = 0.f;
#pragma unroll
        for (int i = 0; i < 8; ++i) d0 += qd[i] * b2f(kc[i]);
        d0 += __shfl_xor(d0, 1);
        d0 += __shfl_xor(d0, 2);
        d0 += __shfl_xor(d0, 4);
        float a0 = d0 * prih;
        float mn0 = fmaxf(m0v, a0);
        float e00 = __expf(m0v - mn0), e01 = __expf(a0 - mn0);
        s0v = s0v * e00 + e01;
#pragma unroll
        for (int i = 0; i < 8; ++i) acc0[i] = acc0[i] * e00 + e01 * b2f(vc[i]);
        m0v = mn0;
    }
    // exact merge of the two chains
    float mn = fmaxf(m0v, m1v);
    float e0 = __expf(m0v - mn), e1 = __expf(m1v - mn);
    float s = s0v * e0 + s1v * e1;
    float inv = (hi > lo) ? 1.f / s : 0.f;
    ushortx8 o;
#pragma unroll
    for (int i = 0; i < 8; ++i) o[i] = f2b((acc0[i] * e0 + acc1[i] * e1) * inv);
    *(ushortx8*)(t_out + qoff) = o;  // overwrite q columns (disjoint from kA/vM reads)
}

// ---------------- host launch ----------------
extern "C" void kernel_launch(void* const* d_in, const int* in_sizes, int n_in,
                              void* d_out, int out_size, void* d_ws, size_t ws_size,
                              hipStream_t stream) {
    (void)in_sizes; (void)n_in; (void)out_size; (void)ws_size;
    const float* h_paper  = (const float*)d_in[0];
    const float* h_author = (const float*)d_in[1];
    const int* src0 = (const int*)d_in[2];
    const int* dst0 = (const int*)d_in[3];
    const int* src1 = (const int*)d_in[4];
    const int* dst1 = (const int*)d_in[5];
    const float* Wk0 = (const float*)d_in[6];  const float* bk0 = (const float*)d_in[7];
    const float* Wq0 = (const float*)d_in[8];  const float* bq0 = (const float*)d_in[9];
    const float* Wv0 = (const float*)d_in[10]; const float* bv0 = (const float*)d_in[11];
    const float* Wa0 = (const float*)d_in[12]; const float* ba0 = (const float*)d_in[13];
    const float* Wk1 = (const float*)d_in[14]; const float* bk1 = (const float*)d_in[15];
    const float* Wq1 = (const float*)d_in[16]; const float* bq1 = (const float*)d_in[17];
    const float* Wv1 = (const float*)d_in[18]; const float* bv1 = (const float*)d_in[19];
    const float* Wa1 = (const float*)d_in[20]; const float* ba1 = (const float*)d_in[21];
    const float* rel_att = (const float*)d_in[22];
    const float* rel_msg = (const float*)d_in[23];
    const float* rel_pri = (const float*)d_in[24];
    const float* skipv   = (const float*)d_in[25];
    float* out = (float*)d_out;

    char* p = (char*)d_ws;
    auto alloc = [&](size_t bytes) -> char* {
        char* r = p;
        p += (bytes + 255) & ~(size_t)255;
        return r;
    };
    ushort_t* hp_pad = (ushort_t*)alloc((size_t)N_PAD * DIM * 2);
    ushort_t* ha_pad = (ushort_t*)alloc((size_t)N_PAD * DIM * 2);
    ushort_t* qkv_p = (ushort_t*)alloc((size_t)N_PAD * QKV_LD * 2);
    ushort_t* qkv_a = (ushort_t*)alloc((size_t)N_PAD * QKV_LD * 2);
    ushort_t* cat_p = (ushort_t*)alloc((size_t)QKV_LD * DIM * 2);
    ushort_t* cat_a = (ushort_t*)alloc((size_t)QKV_LD * DIM * 2);
    ushort_t* WaT0 = (ushort_t*)alloc(DIM * DIM * 2);
    ushort_t* WaT1 = (ushort_t*)alloc(DIM * DIM * 2);
    float* bias_p = (float*)alloc(QKV_LD * 4);
    float* bias_a = (float*)alloc(QKV_LD * 4);
    int* cnt = (int*)alloc((size_t)4 * N_NODES * 4);  // cnt[2N] then fill[2N]
    int* fill = cnt + 2 * N_NODES;
    int* row_ptr = (int*)alloc((size_t)2 * (N_NODES + 1) * 4);
    int* colarr = (int*)alloc((size_t)2 * N_EDGES * 4);

    // prep
    pad_copy2<<<dim3((N_PAD * DIM / 4 + 255) / 256, 2), 256, 0, stream>>>(h_paper, h_author, hp_pad, ha_pad);
    fuse_weights4<<<dim3(1024, 4), 256, 0, stream>>>(Wk0, bk0, Wv0, bv0, Wk1, bk1, Wv1, bv1,
                                                     rel_att, rel_msg, cat_p, cat_a, bias_p, bias_a);
    transpose4<<<dim3(256, 4), 256, 0, stream>>>(Wq0, Wq1, Wa0, Wa1, cat_p, cat_a, WaT0, WaT1);
    copy_biases<<<2, 256, 0, stream>>>(bq0, bq1, bias_p, bias_a);

    // CSR (both relations)
    hipMemsetAsync(cnt, 0, (size_t)4 * N_NODES * 4, stream);
    hist2<<<(2 * N_EDGES + 255) / 256, 256, 0, stream>>>(dst0, dst1, cnt);
    scan2<<<2, 1024, 0, stream>>>(cnt, row_ptr);
    scatter2<<<(2 * N_EDGES + 255) / 256, 256, 0, stream>>>(src0, dst0, src1, dst1, row_ptr, fill, colarr);

    // projections: qkv_p = hp @ [Wq0 | Wk0*A1 | Wv0*M1], qkv_a = ha @ [Wq1 | Wk1*A0 | Wv1*M0]
    gemm_proj<<<5640, 512, 0, stream>>>(hp_pad, ha_pad, cat_p, cat_a, bias_p, bias_a, qkv_p, qkv_a);

    // attention, both relations; t written into q columns of the dst-side qkv
    node_attn<<<dim3(N_PAD / 4, 2), 256, 0, stream>>>(qkv_p, qkv_p, qkv_a, qkv_a, row_ptr, colarr, rel_pri);

    // output GEMMs with sigmoid-skip blend (bf16 residual from hp_pad/ha_pad)
    gemm_out<<<1880, 512, 0, stream>>>(qkv_p, qkv_a, WaT0, WaT1, ba0, ba1,
                                       hp_pad, ha_pad, skipv, out);
}

// Round 7
// 632.624 us; speedup vs baseline: 1.4448x; 1.0074x over previous
//
#include <hip/hip_runtime.h>
#include <hip/hip_bf16.h>
#include <stdint.h>

#define N_NODES 30000
#define N_PAD   30080   // 235 * 128
#define N_EDGES 100000
#define DIM     512
#define QKV_LD  1536    // packed [q | kA | vM] row stride

typedef unsigned short ushort_t;
typedef __attribute__((ext_vector_type(8))) short short8;
typedef __attribute__((ext_vector_type(8))) unsigned short ushortx8;
typedef __attribute__((ext_vector_type(4))) float floatx4;

__device__ __forceinline__ float b2f(ushort_t b) { return __uint_as_float(((unsigned)b) << 16); }
__device__ __forceinline__ ushort_t f2b(float f) {
    unsigned u = __float_as_uint(f);
    u += 0x7FFFu + ((u >> 16) & 1u);   // round-nearest-even
    return (ushort_t)(u >> 16);
}

// ---------------- pad/convert h (f32) into padded bf16 buffers ----------------
__global__ __launch_bounds__(256) void pad_copy2(const float* __restrict__ h0,
                                                 const float* __restrict__ h1,
                                                 ushort_t* __restrict__ d0,
                                                 ushort_t* __restrict__ d1) {
    const int total = N_PAD * DIM / 4;
    const int valid = N_NODES * DIM / 4;
    int idx = blockIdx.x * 256 + threadIdx.x;
    if (idx >= total) return;
    const float* s = blockIdx.y ? h1 : h0;
    ushort_t* d = blockIdx.y ? d1 : d0;
    float4 v = make_float4(0.f, 0.f, 0.f, 0.f);
    if (idx < valid) v = ((const float4*)s)[idx];
    ushort_t o[4] = {f2b(v.x), f2b(v.y), f2b(v.z), f2b(v.w)};
    ((uint2*)d)[idx] = *(const uint2*)o;
}

// ---- fold per-head relation matrix into weight, write into concatenated B^T ----
__global__ __launch_bounds__(256) void fuse_weights4(const float* __restrict__ Wk0, const float* __restrict__ bk0,
                                                     const float* __restrict__ Wv0, const float* __restrict__ bv0,
                                                     const float* __restrict__ Wk1, const float* __restrict__ bk1,
                                                     const float* __restrict__ Wv1, const float* __restrict__ bv1,
                                                     const float* __restrict__ rel_att, const float* __restrict__ rel_msg,
                                                     ushort_t* __restrict__ cat_p, ushort_t* __restrict__ cat_a,
                                                     float* __restrict__ bias_p, float* __restrict__ bias_a) {
    const float *W, *bvec, *A;
    ushort_t* outw; float* outb;
    switch (blockIdx.y) {  // rel0 folds into author-side cat, rel1 into paper-side
        case 0: W = Wk1; bvec = bk1; A = rel_att;          outw = cat_a + 512 * DIM;  outb = bias_a + 512;  break;
        case 1: W = Wv1; bvec = bv1; A = rel_msg;          outw = cat_a + 1024 * DIM; outb = bias_a + 1024; break;
        case 2: W = Wk0; bvec = bk0; A = rel_att + 32768;  outw = cat_p + 512 * DIM;  outb = bias_p + 512;  break;
        default: W = Wv0; bvec = bv0; A = rel_msg + 32768; outw = cat_p + 1024 * DIM; outb = bias_p + 1024; break;
    }
    int idx = blockIdx.x * 256 + threadIdx.x;  // 512*512
    int n = idx & 511;
    int i = idx >> 9;
    int h = n >> 6, d = n & 63;
    const float* wrow = W + i * DIM + h * 64;
    const float* acol = A + h * 4096 + d;
    float s = 0.f;
#pragma unroll 8
    for (int c = 0; c < 64; ++c) s += wrow[c] * acol[c * 64];
    outw[n * DIM + i] = f2b(s);
    if (i == 0) {
        const float* bh = bvec + h * 64;
        float sb = 0.f;
        for (int c = 0; c < 64; ++c) sb += bh[c] * acol[c * 64];
        outb[n] = sb;
    }
}

// ---- 4x 512x512 transpose f32 -> bf16 ----
__global__ __launch_bounds__(256) void transpose4(const float* w0, const float* w1,
                                                  const float* w2, const float* w3,
                                                  ushort_t* o0, ushort_t* o1,
                                                  ushort_t* o2, ushort_t* o3) {
    const float* W; ushort_t* O;
    switch (blockIdx.y) {
        case 0: W = w0; O = o0; break;
        case 1: W = w1; O = o1; break;
        case 2: W = w2; O = o2; break;
        default: W = w3; O = o3; break;
    }
    __shared__ float tile[32][33];
    int bx = blockIdx.x & 15, by = blockIdx.x >> 4;
    int tx = threadIdx.x & 31, ty = threadIdx.x >> 5;  // 32x8
#pragma unroll
    for (int r = 0; r < 32; r += 8) tile[ty + r][tx] = W[(by * 32 + ty + r) * DIM + bx * 32 + tx];
    __syncthreads();
#pragma unroll
    for (int r = 0; r < 32; r += 8) O[(bx * 32 + ty + r) * DIM + by * 32 + tx] = f2b(tile[tx][ty + r]);
}

__global__ __launch_bounds__(256) void copy_biases(const float* bq0, const float* bq1,
                                                   float* bias_p, float* bias_a) {
    int i = blockIdx.x * 256 + threadIdx.x;  // 512
    bias_p[i] = bq0[i];
    bias_a[i] = bq1[i];
}

// ---------------- CSR build (both relations in one pass) ----------------
__global__ __launch_bounds__(256) void hist2(const int* __restrict__ dst0, const int* __restrict__ dst1,
                                             int* __restrict__ cnt) {
    int e = blockIdx.x * 256 + threadIdx.x;
    if (e >= 2 * N_EDGES) return;
    int rel = e >= N_EDGES;
    int d = (rel ? dst1 : dst0)[e - rel * N_EDGES];
    atomicAdd(&cnt[rel * N_NODES + d], 1);
}

__global__ __launch_bounds__(1024) void scan2(const int* __restrict__ cnt, int* __restrict__ row_ptr) {
    int rel = blockIdx.x;
    const int* c = cnt + rel * N_NODES;
    int* rp = row_ptr + rel * (N_NODES + 1);
    __shared__ int sums[1024];
    int tid = threadIdx.x;
    int base = tid * 32;
    int loc[32];
    int s = 0;
#pragma unroll
    for (int i = 0; i < 32; ++i) {
        int idx = base + i;
        int v = (idx < N_NODES) ? c[idx] : 0;
        s += v;
        loc[i] = s;
    }
    sums[tid] = s;
    __syncthreads();
    for (int off = 1; off < 1024; off <<= 1) {
        int add = (tid >= off) ? sums[tid - off] : 0;
        __syncthreads();
        sums[tid] += add;
        __syncthreads();
    }
    int pre = (tid > 0) ? sums[tid - 1] : 0;
    if (tid == 0) rp[0] = 0;
#pragma unroll
    for (int i = 0; i < 32; ++i) {
        int idx = base + i;
        if (idx < N_NODES) rp[idx + 1] = pre + loc[i];
    }
}

__global__ __launch_bounds__(256) void scatter2(const int* __restrict__ src0, const int* __restrict__ dst0,
                                                const int* __restrict__ src1, const int* __restrict__ dst1,
                                                const int* __restrict__ row_ptr,
                                                int* __restrict__ fill,
                                                int* __restrict__ colarr) {
    int e = blockIdx.x * 256 + threadIdx.x;
    if (e >= 2 * N_EDGES) return;
    int rel = e >= N_EDGES;
    int ei = e - rel * N_EDGES;
    int s = (rel ? src1 : src0)[ei];
    int d = (rel ? dst1 : dst0)[ei];
    int pos = atomicAdd(&fill[rel * N_NODES + d], 1);
    colarr[rel * N_EDGES + row_ptr[rel * (N_NODES + 1) + d] + pos] = s;
}

// ---------------- MFMA GEMM core: 128x128 tile, BK=32, 8 waves, 3-buffer counted pipeline ----
// T4: loads for tile t+1 are issued BEFORE barrier t and stay in flight across it;
// each wave waits only vmcnt(2) (its own tile-t pair), never draining the queue.
// Race-freedom: writer targets buf (t+1)%3; concurrent readers are at most one
// step behind (buf (t-1)%3) or current (t%3) -> Nb=3 separates them (d+2 rule).
// Swizzle (R5, verified 0 conflicts): LDS[row][slot] holds global slot^((row>>1)&3).
typedef const __attribute__((address_space(1))) unsigned int gu32;
typedef __attribute__((address_space(3))) unsigned int lu32;
__device__ __forceinline__ void gload_lds16(const void* g, void* l) {
    __builtin_amdgcn_global_load_lds((gu32*)g, (lu32*)l, 16, 0, 0);
}

// projection: C[M,1536] = A[M,512] @ BT[1536,512]^T + bias, bf16 out, ldc=1536
// grid: 1D 5640 = 8 XCD chunks of 705; decode rel / m-blk / n-blk inside.
__global__ __launch_bounds__(512) void gemm_proj(const ushort_t* __restrict__ Ap, const ushort_t* __restrict__ Aa,
                                                 const ushort_t* __restrict__ Bp, const ushort_t* __restrict__ Ba,
                                                 const float* __restrict__ bias_p, const float* __restrict__ bias_a,
                                                 ushort_t* __restrict__ Cp, ushort_t* __restrict__ Ca) {
    int bid = blockIdx.x;
    int lin = (bid & 7) * 705 + (bid >> 3);   // XCD-chunked bijection (5640 = 8*705)
    int rel = lin >= 2820;
    int r = lin - rel * 2820;
    int my = r / 12, nx = r - my * 12;
    const ushort_t* A = rel ? Aa : Ap;
    const ushort_t* BT = rel ? Ba : Bp;
    const float* bias = rel ? bias_a : bias_p;
    ushort_t* C = rel ? Ca : Cp;

    // S[buf][0]=A-tile (8KB), S[buf][1]=B-tile (8KB); 3 buffers = 48KB
    __shared__ alignas(16) ushort_t S[3][2][128 * 32];
    int n0 = nx * 128, m0 = my * 128;
    int tid = threadIdx.x;
    int w = tid >> 6, l = tid & 63;
    int wr = w >> 1, wc = w & 1;          // wave covers rows [wr*32,+32), cols [wc*64,+64)
    int fr = l & 15, fq = l >> 4;
    floatx4 acc[2][4] = {};
    int aXor = (fr >> 1) & 3;             // read-side XOR key (row-invariant: rows step by 16)
    int aoff = ((wr * 32 + fr) * 32 + (fq ^ aXor) * 8) * 2;          // byte offset in A region
    int boff = 8192 + ((wc * 64 + fr) * 32 + (fq ^ aXor) * 8) * 2;   // byte offset in B region
    // staging: thread tq handles rows srow, srow+64 of its matrix half
    int tq = tid & 255;
    int srow = tq >> 2;
    int sc0 = (((tq & 3) ^ ((srow >> 1) & 3))) * 8;   // pre-swizzled global slot
    const ushort_t* gsrc0 = (tid < 256) ? (A + (size_t)(m0 + srow) * DIM + sc0)
                                        : (BT + (size_t)(n0 + srow) * DIM + sc0);
    const ushort_t* gsrc1 = gsrc0 + (size_t)64 * DIM;
    char* sbase = (char*)S + ((tid < 256) ? 0 : 8192) + tq * 16;

    // prologue: tile 0 -> buffer 0
    gload_lds16(gsrc0, sbase);
    gload_lds16(gsrc1, sbase + 4096);

    int cur = 0, nxt = 1;
#pragma unroll 1
    for (int kt = 0; kt < 16; ++kt) {
        if (kt < 15) {
            int k1 = (kt + 1) * 32;
            char* d = sbase + nxt * 16384;
            gload_lds16(gsrc0 + k1, d);
            gload_lds16(gsrc1 + k1, d + 4096);
            asm volatile("s_waitcnt vmcnt(2)" ::: "memory");   // tile kt landed, kt+1 flying
        } else {
            asm volatile("s_waitcnt vmcnt(0)" ::: "memory");
        }
        __builtin_amdgcn_sched_barrier(0);
        __builtin_amdgcn_s_barrier();
        __builtin_amdgcn_sched_barrier(0);
        const ushort_t* aF = (const ushort_t*)((const char*)S + cur * 16384 + aoff);
        const ushort_t* bF = (const ushort_t*)((const char*)S + cur * 16384 + boff);
        short8 af[2], bf[4];
#pragma unroll
        for (int i = 0; i < 2; ++i) af[i] = *(const short8*)(aF + i * 16 * 32);
#pragma unroll
        for (int j = 0; j < 4; ++j) bf[j] = *(const short8*)(bF + j * 16 * 32);
#pragma unroll
        for (int i = 0; i < 2; ++i)
#pragma unroll
            for (int j = 0; j < 4; ++j)
                acc[i][j] = __builtin_amdgcn_mfma_f32_16x16x32_bf16(af[i], bf[j], acc[i][j], 0, 0, 0);
        cur = nxt; nxt = (nxt == 2) ? 0 : nxt + 1;
    }
#pragma unroll
    for (int i = 0; i < 2; ++i)
#pragma unroll
        for (int j = 0; j < 4; ++j) {
            int col = n0 + wc * 64 + j * 16 + fr;
            float bc = bias[col];
#pragma unroll
            for (int rr = 0; rr < 4; ++rr) {
                int grow = m0 + wr * 32 + i * 16 + fq * 4 + rr;
                C[(size_t)grow * QKV_LD + col] = f2b(acc[i][j][rr] + bc);
            }
        }
}

// out: C[M,512] = T[M,512](lda=1536) @ WaT^T + ba, sigmoid-skip blend vs bf16 residual
// grid: 1D 1880 = 8 XCD chunks of 235.
__global__ __launch_bounds__(512) void gemm_out(const ushort_t* __restrict__ Tp, const ushort_t* __restrict__ Ta,
                                                const ushort_t* __restrict__ Wp, const ushort_t* __restrict__ Wa,
                                                const float* __restrict__ ba0, const float* __restrict__ ba1,
                                                const ushort_t* __restrict__ hp, const ushort_t* __restrict__ ha,
                                                const float* __restrict__ skipv, float* __restrict__ out) {
    int bid = blockIdx.x;
    int lin = (bid & 7) * 235 + (bid >> 3);   // XCD-chunked bijection (1880 = 8*235)
    int rel = lin >= 940;
    int r = lin - rel * 940;
    int my = r >> 2, nx = r & 3;
    const ushort_t* A = rel ? Ta : Tp;
    const ushort_t* BT = rel ? Wa : Wp;
    const float* bias = rel ? ba1 : ba0;
    const ushort_t* Hres = rel ? ha : hp;   // bf16 padded residual
    float* C = out + (size_t)rel * N_NODES * DIM;

    __shared__ alignas(16) ushort_t S[3][2][128 * 32];
    int n0 = nx * 128, m0 = my * 128;
    int tid = threadIdx.x;
    int w = tid >> 6, l = tid & 63;
    int wr = w >> 1, wc = w & 1;
    int fr = l & 15, fq = l >> 4;
    floatx4 acc[2][4] = {};
    int aXor = (fr >> 1) & 3;
    int aoff = ((wr * 32 + fr) * 32 + (fq ^ aXor) * 8) * 2;
    int boff = 8192 + ((wc * 64 + fr) * 32 + (fq ^ aXor) * 8) * 2;
    int tq = tid & 255;
    int srow = tq >> 2;
    int sc0 = (((tq & 3) ^ ((srow >> 1) & 3))) * 8;
    size_t lda = (tid < 256) ? (size_t)QKV_LD : (size_t)DIM;
    const ushort_t* gsrc0 = (tid < 256) ? (A + (size_t)(m0 + srow) * QKV_LD + sc0)
                                        : (BT + (size_t)(n0 + srow) * DIM + sc0);
    const ushort_t* gsrc1 = gsrc0 + (size_t)64 * lda;
    char* sbase = (char*)S + ((tid < 256) ? 0 : 8192) + tq * 16;

    gload_lds16(gsrc0, sbase);
    gload_lds16(gsrc1, sbase + 4096);

    int cur = 0, nxt = 1;
#pragma unroll 1
    for (int kt = 0; kt < 16; ++kt) {
        if (kt < 15) {
            int k1 = (kt + 1) * 32;
            char* d = sbase + nxt * 16384;
            gload_lds16(gsrc0 + k1, d);
            gload_lds16(gsrc1 + k1, d + 4096);
            asm volatile("s_waitcnt vmcnt(2)" ::: "memory");
        } else {
            asm volatile("s_waitcnt vmcnt(0)" ::: "memory");
        }
        __builtin_amdgcn_sched_barrier(0);
        __builtin_amdgcn_s_barrier();
        __builtin_amdgcn_sched_barrier(0);
        const ushort_t* aF = (const ushort_t*)((const char*)S + cur * 16384 + aoff);
        const ushort_t* bF = (const ushort_t*)((const char*)S + cur * 16384 + boff);
        short8 af[2], bf[4];
#pragma unroll
        for (int i = 0; i < 2; ++i) af[i] = *(const short8*)(aF + i * 16 * 32);
#pragma unroll
        for (int j = 0; j < 4; ++j) bf[j] = *(const short8*)(bF + j * 16 * 32);
#pragma unroll
        for (int i = 0; i < 2; ++i)
#pragma unroll
            for (int j = 0; j < 4; ++j)
                acc[i][j] = __builtin_amdgcn_mfma_f32_16x16x32_bf16(af[i], bf[j], acc[i][j], 0, 0, 0);
        cur = nxt; nxt = (nxt == 2) ? 0 : nxt + 1;
    }
    float sk = skipv[rel];
    float alpha = 1.f / (1.f + __expf(-sk));
    float onem = 1.f - alpha;
#pragma unroll
    for (int i = 0; i < 2; ++i)
#pragma unroll
        for (int j = 0; j < 4; ++j) {
            int col = n0 + wc * 64 + j * 16 + fr;
            float bc = bias[col];
#pragma unroll
            for (int rr = 0; rr < 4; ++rr) {
                int grow = m0 + wr * 32 + i * 16 + fq * 4 + rr;
                if (grow < N_NODES) {
                    float v = acc[i][j][rr] + bc;
                    float hres = b2f(Hres[(size_t)grow * DIM + col]);
                    C[(size_t)grow * DIM + col] = v * alpha + hres * onem;
                }
            }
        }
}

// ------- per-node online-softmax aggregation: one wave = one node, all 8 heads -------
// (R5 single-chain form: low VGPR -> full latency-hiding occupancy; one-edge lookahead)
__global__ __launch_bounds__(256) void node_attn(const ushort_t* __restrict__ qkv_p,
                                                 ushort_t* __restrict__ qkv_p_mut,
                                                 const ushort_t* __restrict__ qkv_a,
                                                 ushort_t* __restrict__ qkv_a_mut,
                                                 const int* __restrict__ row_ptr,
                                                 const int* __restrict__ colarr,
                                                 const float* __restrict__ rel_pri) {
    int rel = blockIdx.y;
    const ushort_t* qkv_dst = rel ? qkv_a : qkv_p;
    ushort_t* t_out = rel ? qkv_a_mut : qkv_p_mut;
    const ushort_t* qkv_src = rel ? qkv_p : qkv_a;
    const int* rp = row_ptr + rel * (N_NODES + 1);
    const int* col = colarr + rel * N_EDGES;
    const float* pri = rel_pri + rel * 8;

    int w = threadIdx.x >> 6, l = threadIdx.x & 63;
    int n = blockIdx.x * 4 + w;  // < N_PAD
    float prih = pri[l >> 3] * 0.125f;  // pri[h] / sqrt(64)

    size_t qoff = (size_t)n * QKV_LD + l * 8;
    ushortx8 qr = *(const ushortx8*)(qkv_dst + qoff);
    float qd[8];
#pragma unroll
    for (int i = 0; i < 8; ++i) qd[i] = b2f(qr[i]);

    int lo = 0, hi = 0;
    if (n < N_NODES) { lo = rp[n]; hi = rp[n + 1]; }

    float m = -3.0e38f, s = 0.f;
    float acc[8] = {};
    int j = lo;
    ushortx8 kr, vr;
    if (j < hi) {
        int sn = col[j];
        const ushort_t* kb = qkv_src + (size_t)sn * QKV_LD + 512 + l * 8;
        kr = *(const ushortx8*)kb;
        vr = *(const ushortx8*)(kb + 512);
    }
    while (j < hi) {
        ushortx8 kc = kr, vc = vr;
        ++j;
        if (j < hi) {  // one-edge lookahead
            int sn = col[j];
            const ushort_t* kb = qkv_src + (size_t)sn * QKV_LD + 512 + l * 8;
            kr = *(const ushortx8*)kb;
            vr = *(const ushortx8*)(kb + 512);
        }
        float dot = 0.f;
#pragma unroll
        for (int i = 0; i < 8; ++i) dot += qd[i] * b2f(kc[i]);
        dot += __shfl_xor(dot, 1);
        dot += __shfl_xor(dot, 2);
        dot += __shfl_xor(dot, 4);   // full head-dot, replicated across 8-lane group
        float att = dot * prih;
        float mn = fmaxf(m, att);
        float e0 = __expf(m - mn);
        float e1 = __expf(att - mn);
        s = s * e0 + e1;
#pragma unroll
        for (int i = 0; i < 8; ++i) acc[i] = acc[i] * e0 + e1 * b2f(vc[i]);
        m = mn;
    }
    float inv = (hi > lo) ? 1.f / s : 0.f;
    ushortx8 o;
#pragma unroll
    for (int i = 0; i < 8; ++i) o[i] = f2b(acc[i] * inv);
    *(ushortx8*)(t_out + qoff) = o;  // overwrite q columns (disjoint from kA/vM reads)
}

// ---------------- host launch ----------------
extern "C" void kernel_launch(void* const* d_in, const int* in_sizes, int n_in,
                              void* d_out, int out_size, void* d_ws, size_t ws_size,
                              hipStream_t stream) {
    (void)in_sizes; (void)n_in; (void)out_size; (void)ws_size;
    const float* h_paper  = (const float*)d_in[0];
    const float* h_author = (const float*)d_in[1];
    const int* src0 = (const int*)d_in[2];
    const int* dst0 = (const int*)d_in[3];
    const int* src1 = (const int*)d_in[4];
    const int* dst1 = (const int*)d_in[5];
    const float* Wk0 = (const float*)d_in[6];  const float* bk0 = (const float*)d_in[7];
    const float* Wq0 = (const float*)d_in[8];  const float* bq0 = (const float*)d_in[9];
    const float* Wv0 = (const float*)d_in[10]; const float* bv0 = (const float*)d_in[11];
    const float* Wa0 = (const float*)d_in[12]; const float* ba0 = (const float*)d_in[13];
    const float* Wk1 = (const float*)d_in[14]; const float* bk1 = (const float*)d_in[15];
    const float* Wq1 = (const float*)d_in[16]; const float* bq1 = (const float*)d_in[17];
    const float* Wv1 = (const float*)d_in[18]; const float* bv1 = (const float*)d_in[19];
    const float* Wa1 = (const float*)d_in[20]; const float* ba1 = (const float*)d_in[21];
    const float* rel_att = (const float*)d_in[22];
    const float* rel_msg = (const float*)d_in[23];
    const float* rel_pri = (const float*)d_in[24];
    const float* skipv   = (const float*)d_in[25];
    float* out = (float*)d_out;

    char* p = (char*)d_ws;
    auto alloc = [&](size_t bytes) -> char* {
        char* r = p;
        p += (bytes + 255) & ~(size_t)255;
        return r;
    };
    ushort_t* hp_pad = (ushort_t*)alloc((size_t)N_PAD * DIM * 2);
    ushort_t* ha_pad = (ushort_t*)alloc((size_t)N_PAD * DIM * 2);
    ushort_t* qkv_p = (ushort_t*)alloc((size_t)N_PAD * QKV_LD * 2);
    ushort_t* qkv_a = (ushort_t*)alloc((size_t)N_PAD * QKV_LD * 2);
    ushort_t* cat_p = (ushort_t*)alloc((size_t)QKV_LD * DIM * 2);
    ushort_t* cat_a = (ushort_t*)alloc((size_t)QKV_LD * DIM * 2);
    ushort_t* WaT0 = (ushort_t*)alloc(DIM * DIM * 2);
    ushort_t* WaT1 = (ushort_t*)alloc(DIM * DIM * 2);
    float* bias_p = (float*)alloc(QKV_LD * 4);
    float* bias_a = (float*)alloc(QKV_LD * 4);
    int* cnt = (int*)alloc((size_t)4 * N_NODES * 4);  // cnt[2N] then fill[2N]
    int* fill = cnt + 2 * N_NODES;
    int* row_ptr = (int*)alloc((size_t)2 * (N_NODES + 1) * 4);
    int* colarr = (int*)alloc((size_t)2 * N_EDGES * 4);

    // prep
    pad_copy2<<<dim3((N_PAD * DIM / 4 + 255) / 256, 2), 256, 0, stream>>>(h_paper, h_author, hp_pad, ha_pad);
    fuse_weights4<<<dim3(1024, 4), 256, 0, stream>>>(Wk0, bk0, Wv0, bv0, Wk1, bk1, Wv1, bv1,
                                                     rel_att, rel_msg, cat_p, cat_a, bias_p, bias_a);
    transpose4<<<dim3(256, 4), 256, 0, stream>>>(Wq0, Wq1, Wa0, Wa1, cat_p, cat_a, WaT0, WaT1);
    copy_biases<<<2, 256, 0, stream>>>(bq0, bq1, bias_p, bias_a);

    // CSR (both relations)
    hipMemsetAsync(cnt, 0, (size_t)4 * N_NODES * 4, stream);
    hist2<<<(2 * N_EDGES + 255) / 256, 256, 0, stream>>>(dst0, dst1, cnt);
    scan2<<<2, 1024, 0, stream>>>(cnt, row_ptr);
    scatter2<<<(2 * N_EDGES + 255) / 256, 256, 0, stream>>>(src0, dst0, src1, dst1, row_ptr, fill, colarr);

    // projections: qkv_p = hp @ [Wq0 | Wk0*A1 | Wv0*M1], qkv_a = ha @ [Wq1 | Wk1*A0 | Wv1*M0]
    gemm_proj<<<5640, 512, 0, stream>>>(hp_pad, ha_pad, cat_p, cat_a, bias_p, bias_a, qkv_p, qkv_a);

    // attention, both relations; t written into q columns of the dst-side qkv
    node_attn<<<dim3(N_PAD / 4, 2), 256, 0, stream>>>(qkv_p, qkv_p, qkv_a, qkv_a, row_ptr, colarr, rel_pri);

    // output GEMMs with sigmoid-skip blend (bf16 residual from hp_pad/ha_pad)
    gemm_out<<<1880, 512, 0, stream>>>(qkv_p, qkv_a, WaT0, WaT1, ba0, ba1,
                                       hp_pad, ha_pad, skipv, out);
}